// Round 1
// baseline (466.042 us; speedup 1.0000x reference)
//
#include <hip/hip_runtime.h>
#include <math.h>

#define D_MODEL 1024
#define NHEADS 16
#define HDIM 64
#define BATCH 2
#define SEQ 2048
#define MROWS (BATCH * SEQ)  // 4096

typedef unsigned int uint32;
typedef __attribute__((ext_vector_type(8))) short short8;
typedef __attribute__((ext_vector_type(4))) float f32x4;

__device__ __forceinline__ unsigned short f2bf(float f) {
  unsigned int u = __float_as_uint(f);
  u += 0x7fffu + ((u >> 16) & 1u);
  return (unsigned short)(u >> 16);
}

// ---------------------------------------------------------------------------
// Kernel 1: convert 4 weights fp32 [K][N] -> bf16 transposed [N][K]
// ---------------------------------------------------------------------------
struct WtArgs { const float* src[4]; };

__global__ __launch_bounds__(256) void wt_kernel(WtArgs args, unsigned short* dst) {
  const float* W = args.src[blockIdx.z];
  unsigned short* WT = dst + (size_t)blockIdx.z * (D_MODEL * D_MODEL);
  __shared__ unsigned short tile[64][80];
  int t = threadIdx.x;
  int r = t >> 2, cc = (t & 3) * 16;
  int k0 = blockIdx.y * 64, n0 = blockIdx.x * 64;
  const float* src = W + (size_t)(k0 + r) * D_MODEL + n0 + cc;
#pragma unroll
  for (int j = 0; j < 16; j += 4) {
    float4 v = *(const float4*)(src + j);
    tile[r][cc + j + 0] = f2bf(v.x);
    tile[r][cc + j + 1] = f2bf(v.y);
    tile[r][cc + j + 2] = f2bf(v.z);
    tile[r][cc + j + 3] = f2bf(v.w);
  }
  __syncthreads();
  __align__(16) unsigned short tmp[16];
#pragma unroll
  for (int j = 0; j < 16; ++j) tmp[j] = tile[cc + j][r];
  unsigned short* d = WT + (size_t)(n0 + r) * D_MODEL + k0 + cc;
  *(uint4*)d = ((uint4*)tmp)[0];
  *(uint4*)(d + 8) = ((uint4*)tmp)[1];
}

// ---------------------------------------------------------------------------
// Kernel 2/5: GEMM  C[M,N] = A[M,K] * WT[N,K]^T + bias
//   128x128 tile, BK=64, 4 waves (2x2 of 64x64), mfma_f32_16x16x32_bf16
//   LDS XOR-swizzle: byte_col ^= (row&7)<<4  (rows are 128B)
// ---------------------------------------------------------------------------
struct GemmArgs {
  const void* A[3];
  const unsigned short* W[3];
  const float* bias[3];
  void* C[3];
};

template <bool A_F32, bool OUT_F32>
__global__ __launch_bounds__(256) void gemm_kernel(GemmArgs args) {
  int z = blockIdx.z;
  const unsigned short* WT = args.W[z];
  const float* bias = args.bias[z];
  int n0 = blockIdx.x * 128, m0 = blockIdx.y * 128;
  __shared__ __align__(16) char As[128 * 128];
  __shared__ __align__(16) char Bs[128 * 128];
  int t = threadIdx.x;
  int wave = t >> 6, lane = t & 63;
  int wm = (wave >> 1) * 64, wn = (wave & 1) * 64;
  int lr = lane & 15, lg = lane >> 4;
  f32x4 acc[4][4] = {};

  for (int kt = 0; kt < D_MODEL; kt += 64) {
#pragma unroll
    for (int c = 0; c < 4; ++c) {
      int idx = t + 256 * c;
      int row = idx >> 3, ch = idx & 7;
      int cb = (ch * 16) ^ ((row & 7) << 4);
      uint4 bv = *(const uint4*)(WT + (size_t)(n0 + row) * D_MODEL + kt + ch * 8);
      *(uint4*)(Bs + row * 128 + cb) = bv;
      uint4 av;
      if (A_F32) {
        const float* A = (const float*)args.A[z];
        const float* ap = A + (size_t)(m0 + row) * D_MODEL + kt + ch * 8;
        float4 v0 = *(const float4*)ap;
        float4 v1 = *(const float4*)(ap + 4);
        av.x = (uint32)f2bf(v0.x) | ((uint32)f2bf(v0.y) << 16);
        av.y = (uint32)f2bf(v0.z) | ((uint32)f2bf(v0.w) << 16);
        av.z = (uint32)f2bf(v1.x) | ((uint32)f2bf(v1.y) << 16);
        av.w = (uint32)f2bf(v1.z) | ((uint32)f2bf(v1.w) << 16);
      } else {
        const unsigned short* A = (const unsigned short*)args.A[z];
        av = *(const uint4*)(A + (size_t)(m0 + row) * D_MODEL + kt + ch * 8);
      }
      *(uint4*)(As + row * 128 + cb) = av;
    }
    __syncthreads();
    short8 af[4][2], bf[4][2];
#pragma unroll
    for (int f = 0; f < 4; ++f) {
#pragma unroll
      for (int kk = 0; kk < 2; ++kk) {
        int ra = wm + f * 16 + lr;
        af[f][kk] = *(const short8*)(As + ra * 128 + ((kk * 64 + lg * 16) ^ ((ra & 7) << 4)));
        int rb = wn + f * 16 + lr;
        bf[f][kk] = *(const short8*)(Bs + rb * 128 + ((kk * 64 + lg * 16) ^ ((rb & 7) << 4)));
      }
    }
#pragma unroll
    for (int i = 0; i < 4; ++i)
#pragma unroll
      for (int j = 0; j < 4; ++j)
#pragma unroll
        for (int kk = 0; kk < 2; ++kk)
          acc[i][j] = __builtin_amdgcn_mfma_f32_16x16x32_bf16(af[i][kk], bf[j][kk], acc[i][j], 0, 0, 0);
    __syncthreads();
  }
#pragma unroll
  for (int i = 0; i < 4; ++i)
#pragma unroll
    for (int j = 0; j < 4; ++j) {
      int col = n0 + wn + j * 16 + lr;
      float bb = bias[col];
#pragma unroll
      for (int r = 0; r < 4; ++r) {
        int row = m0 + wm + i * 16 + lg * 4 + r;
        float v = acc[i][j][r] + bb;
        if (OUT_F32)
          ((float*)args.C[z])[(size_t)row * D_MODEL + col] = v;
        else
          ((unsigned short*)args.C[z])[(size_t)row * D_MODEL + col] = f2bf(v);
      }
    }
}

// ---------------------------------------------------------------------------
// Kernel 3: V [B*S, D] bf16 -> Vt [(b*H+h)*64 + dh][S] bf16
// ---------------------------------------------------------------------------
__global__ __launch_bounds__(256) void vt_kernel(const unsigned short* V, unsigned short* Vt) {
  int bh = blockIdx.y;
  int b = bh >> 4;
  int h = bh & 15;
  int s0 = blockIdx.x * 64;
  __shared__ unsigned short tile[64][80];
  int t = threadIdx.x;
  int r = t >> 2, c = (t & 3) * 16;
  const unsigned short* src = V + (size_t)(b * SEQ + s0 + r) * D_MODEL + h * HDIM + c;
  __align__(16) unsigned short buf[16];
  ((uint4*)buf)[0] = *(const uint4*)src;
  ((uint4*)buf)[1] = *(const uint4*)(src + 8);
#pragma unroll
  for (int j = 0; j < 16; ++j) tile[r][c + j] = buf[j];
  __syncthreads();
  __align__(16) unsigned short tmp[16];
#pragma unroll
  for (int j = 0; j < 16; ++j) tmp[j] = tile[c + j][r];
  unsigned short* dst = Vt + ((size_t)bh * HDIM + r) * SEQ + s0 + c;
  *(uint4*)dst = ((uint4*)tmp)[0];
  *(uint4*)(dst + 8) = ((uint4*)tmp)[1];
}

// ---------------------------------------------------------------------------
// Kernel 4: two-pass attention per (b,h,q-tile of 64). 4 waves x 16 q-rows.
//   pass 1: online row max / sum-exp (no S*S storage)
//   pass 2: recompute scores, write normalized attention fp32, PV via MFMA
// ---------------------------------------------------------------------------
__global__ __launch_bounds__(256) void attn_kernel(const unsigned short* Q, const unsigned short* K,
                                                   const unsigned short* Vt, float* attn,
                                                   unsigned short* ctx) {
  int bh = blockIdx.y;
  int b = bh >> 4;
  int h = bh & 15;
  int q0 = blockIdx.x * 64;
  int t = threadIdx.x, wave = t >> 6, lane = t & 63;
  int lr = lane & 15, lg = lane >> 4;
  __shared__ __align__(16) char Ks[64 * 128];
  __shared__ __align__(16) char Vs[64 * 128];
  __shared__ __align__(16) char Ps[4][16 * 128];

  // Q fragments (stay in registers for the whole block)
  short8 aq[2];
  int qrow = b * SEQ + q0 + wave * 16 + lr;
#pragma unroll
  for (int kk = 0; kk < 2; ++kk)
    aq[kk] = *(const short8*)(Q + (size_t)qrow * D_MODEL + h * HDIM + kk * 32 + lg * 8);

  float mreg[4], lreg[4];
#pragma unroll
  for (int r = 0; r < 4; ++r) { mreg[r] = -INFINITY; lreg[r] = 0.f; }

  // ---- pass 1: row max + sum of exp ----
  for (int kt = 0; kt < SEQ; kt += 64) {
#pragma unroll
    for (int c = 0; c < 2; ++c) {
      int idx = t + 256 * c;
      int row = idx >> 3, ch = idx & 7;
      uint4 kv = *(const uint4*)(K + (size_t)(b * SEQ + kt + row) * D_MODEL + h * HDIM + ch * 8);
      *(uint4*)(Ks + row * 128 + ((ch * 16) ^ ((row & 7) << 4))) = kv;
    }
    __syncthreads();
    f32x4 st[4] = {};
#pragma unroll
    for (int n = 0; n < 4; ++n)
#pragma unroll
      for (int kk = 0; kk < 2; ++kk) {
        int kr = n * 16 + lr;
        short8 bk = *(const short8*)(Ks + kr * 128 + ((kk * 64 + lg * 16) ^ ((kr & 7) << 4)));
        st[n] = __builtin_amdgcn_mfma_f32_16x16x32_bf16(aq[kk], bk, st[n], 0, 0, 0);
      }
#pragma unroll
    for (int n = 0; n < 4; ++n) st[n] *= 0.125f;
#pragma unroll
    for (int r = 0; r < 4; ++r) {
      float v = fmaxf(fmaxf(st[0][r], st[1][r]), fmaxf(st[2][r], st[3][r]));
      v = fmaxf(v, __shfl_xor(v, 1, 64));
      v = fmaxf(v, __shfl_xor(v, 2, 64));
      v = fmaxf(v, __shfl_xor(v, 4, 64));
      v = fmaxf(v, __shfl_xor(v, 8, 64));
      float mnew = fmaxf(mreg[r], v);
      float s = expf(st[0][r] - mnew) + expf(st[1][r] - mnew) +
                expf(st[2][r] - mnew) + expf(st[3][r] - mnew);
      s += __shfl_xor(s, 1, 64);
      s += __shfl_xor(s, 2, 64);
      s += __shfl_xor(s, 4, 64);
      s += __shfl_xor(s, 8, 64);
      lreg[r] = lreg[r] * expf(mreg[r] - mnew) + s;
      mreg[r] = mnew;
    }
    __syncthreads();
  }
  float invl[4];
#pragma unroll
  for (int r = 0; r < 4; ++r) invl[r] = 1.f / lreg[r];

  // ---- pass 2: recompute, write attention, accumulate PV ----
  f32x4 oacc[4] = {};
  float* attn_base = attn + (size_t)bh * SEQ * SEQ;
  for (int kt = 0; kt < SEQ; kt += 64) {
#pragma unroll
    for (int c = 0; c < 2; ++c) {
      int idx = t + 256 * c;
      int row = idx >> 3, ch = idx & 7;
      int cb = (ch * 16) ^ ((row & 7) << 4);
      uint4 kv = *(const uint4*)(K + (size_t)(b * SEQ + kt + row) * D_MODEL + h * HDIM + ch * 8);
      *(uint4*)(Ks + row * 128 + cb) = kv;
      uint4 vv = *(const uint4*)(Vt + ((size_t)bh * HDIM + row) * SEQ + kt + ch * 8);
      *(uint4*)(Vs + row * 128 + cb) = vv;
    }
    __syncthreads();
    f32x4 st[4] = {};
#pragma unroll
    for (int n = 0; n < 4; ++n)
#pragma unroll
      for (int kk = 0; kk < 2; ++kk) {
        int kr = n * 16 + lr;
        short8 bk = *(const short8*)(Ks + kr * 128 + ((kk * 64 + lg * 16) ^ ((kr & 7) << 4)));
        st[n] = __builtin_amdgcn_mfma_f32_16x16x32_bf16(aq[kk], bk, st[n], 0, 0, 0);
      }
#pragma unroll
    for (int n = 0; n < 4; ++n) st[n] *= 0.125f;
#pragma unroll
    for (int n = 0; n < 4; ++n)
#pragma unroll
      for (int r = 0; r < 4; ++r) {
        float p = expf(st[n][r] - mreg[r]) * invl[r];
        int qr = q0 + wave * 16 + lg * 4 + r;
        attn_base[(size_t)qr * SEQ + kt + n * 16 + lr] = p;
        int prow = lg * 4 + r;
        *(unsigned short*)(Ps[wave] + prow * 128 + ((n * 32 + lr * 2) ^ ((prow & 7) << 4))) = f2bf(p);
      }
    // PV: A = P (16 x 64), B = V (64 x 64) read via Vt tile
    short8 ap[2];
#pragma unroll
    for (int kk = 0; kk < 2; ++kk)
      ap[kk] = *(const short8*)(Ps[wave] + lr * 128 + ((kk * 64 + lg * 16) ^ ((lr & 7) << 4)));
#pragma unroll
    for (int n2 = 0; n2 < 4; ++n2)
#pragma unroll
      for (int kk = 0; kk < 2; ++kk) {
        int vr = n2 * 16 + lr;
        short8 bv = *(const short8*)(Vs + vr * 128 + ((kk * 64 + lg * 16) ^ ((vr & 7) << 4)));
        oacc[n2] = __builtin_amdgcn_mfma_f32_16x16x32_bf16(ap[kk], bv, oacc[n2], 0, 0, 0);
      }
    __syncthreads();
  }
#pragma unroll
  for (int n2 = 0; n2 < 4; ++n2)
#pragma unroll
    for (int r = 0; r < 4; ++r) {
      int row = b * SEQ + q0 + wave * 16 + lg * 4 + r;
      ctx[(size_t)row * D_MODEL + h * HDIM + n2 * 16 + lr] = f2bf(oacc[n2][r]);
    }
}

// ---------------------------------------------------------------------------
extern "C" void kernel_launch(void* const* d_in, const int* in_sizes, int n_in,
                              void* d_out, int out_size, void* d_ws, size_t ws_size,
                              hipStream_t stream) {
  const float* query = (const float*)d_in[0];
  const float* key   = (const float*)d_in[1];
  const float* value = (const float*)d_in[2];
  const float* Wq = (const float*)d_in[3];
  const float* bq = (const float*)d_in[4];
  const float* Wk = (const float*)d_in[5];
  const float* bk = (const float*)d_in[6];
  const float* Wv = (const float*)d_in[7];
  const float* bv = (const float*)d_in[8];
  const float* Wo = (const float*)d_in[9];
  const float* bo = (const float*)d_in[10];

  char* ws = (char*)d_ws;
  const size_t MB = (size_t)1 << 20;
  unsigned short* WqT = (unsigned short*)(ws + 0 * MB);
  unsigned short* WkT = (unsigned short*)(ws + 2 * MB);
  unsigned short* WvT = (unsigned short*)(ws + 4 * MB);
  unsigned short* WoT = (unsigned short*)(ws + 6 * MB);
  unsigned short* Qw  = (unsigned short*)(ws + 8 * MB);
  unsigned short* Kw  = (unsigned short*)(ws + 16 * MB);
  unsigned short* Vw  = (unsigned short*)(ws + 24 * MB);
  unsigned short* Vtw = (unsigned short*)(ws + 32 * MB);
  unsigned short* Cw  = (unsigned short*)(ws + 40 * MB);

  float* out0 = (float*)d_out;
  float* attn = out0 + (size_t)MROWS * D_MODEL;

  // 1. weight transpose + bf16 convert
  WtArgs wa;
  wa.src[0] = Wq; wa.src[1] = Wk; wa.src[2] = Wv; wa.src[3] = Wo;
  wt_kernel<<<dim3(16, 16, 4), 256, 0, stream>>>(wa, WqT);

  // 2. QKV projections (batched over z)
  GemmArgs ga;
  ga.A[0] = query; ga.A[1] = key; ga.A[2] = value;
  ga.W[0] = WqT; ga.W[1] = WkT; ga.W[2] = WvT;
  ga.bias[0] = bq; ga.bias[1] = bk; ga.bias[2] = bv;
  ga.C[0] = Qw; ga.C[1] = Kw; ga.C[2] = Vw;
  gemm_kernel<true, false><<<dim3(8, 32, 3), 256, 0, stream>>>(ga);

  // 3. V transpose per (b,h)
  vt_kernel<<<dim3(32, 32), 256, 0, stream>>>(Vw, Vtw);

  // 4. attention (writes attention matrix fp32 + context bf16)
  attn_kernel<<<dim3(32, 32), 256, 0, stream>>>(Qw, Kw, Vtw, attn, Cw);

  // 5. output projection -> fp32 d_out
  GemmArgs go;
  go.A[0] = Cw; go.A[1] = Cw; go.A[2] = Cw;
  go.W[0] = WoT; go.W[1] = WoT; go.W[2] = WoT;
  go.bias[0] = bo; go.bias[1] = bo; go.bias[2] = bo;
  go.C[0] = d_out; go.C[1] = d_out; go.C[2] = d_out;
  gemm_kernel<false, true><<<dim3(8, 32, 1), 256, 0, stream>>>(go);
}

// Round 2
// 335.359 us; speedup vs baseline: 1.3897x; 1.3897x over previous
//
#include <hip/hip_runtime.h>
#include <math.h>

#define D_MODEL 1024
#define NHEADS 16
#define HDIM 64
#define BATCH 2
#define SEQ 2048
#define MROWS (BATCH * SEQ)  // 4096

typedef unsigned int uint32;
typedef __attribute__((ext_vector_type(8))) short short8;
typedef __attribute__((ext_vector_type(4))) float f32x4;

__device__ __forceinline__ unsigned short f2bf(float f) {
  unsigned int u = __float_as_uint(f);
  u += 0x7fffu + ((u >> 16) & 1u);
  return (unsigned short)(u >> 16);
}

__device__ __forceinline__ float fexp2(float x) {
  float r;
  asm("v_exp_f32 %0, %1" : "=v"(r) : "v"(x));
  return r;
}

// ---------------------------------------------------------------------------
// Kernel 1: convert 4 weights fp32 [K][N] -> bf16 transposed [N][K]
// ---------------------------------------------------------------------------
struct WtArgs { const float* src[4]; };

__global__ __launch_bounds__(256) void wt_kernel(WtArgs args, unsigned short* dst) {
  const float* W = args.src[blockIdx.z];
  unsigned short* WT = dst + (size_t)blockIdx.z * (D_MODEL * D_MODEL);
  __shared__ unsigned short tile[64][80];
  int t = threadIdx.x;
  int r = t >> 2, cc = (t & 3) * 16;
  int k0 = blockIdx.y * 64, n0 = blockIdx.x * 64;
  const float* src = W + (size_t)(k0 + r) * D_MODEL + n0 + cc;
#pragma unroll
  for (int j = 0; j < 16; j += 4) {
    float4 v = *(const float4*)(src + j);
    tile[r][cc + j + 0] = f2bf(v.x);
    tile[r][cc + j + 1] = f2bf(v.y);
    tile[r][cc + j + 2] = f2bf(v.z);
    tile[r][cc + j + 3] = f2bf(v.w);
  }
  __syncthreads();
  __align__(16) unsigned short tmp[16];
#pragma unroll
  for (int j = 0; j < 16; ++j) tmp[j] = tile[cc + j][r];
  unsigned short* d = WT + (size_t)(n0 + r) * D_MODEL + k0 + cc;
  *(uint4*)d = ((uint4*)tmp)[0];
  *(uint4*)(d + 8) = ((uint4*)tmp)[1];
}

// ---------------------------------------------------------------------------
// Kernel 2/5: GEMM  C[M,N] = A[M,K] * WT[N,K]^T + bias
// ---------------------------------------------------------------------------
struct GemmArgs {
  const void* A[3];
  const unsigned short* W[3];
  const float* bias[3];
  void* C[3];
};

template <bool A_F32, bool OUT_F32>
__global__ __launch_bounds__(256) void gemm_kernel(GemmArgs args) {
  int z = blockIdx.z;
  const unsigned short* WT = args.W[z];
  const float* bias = args.bias[z];
  int n0 = blockIdx.x * 128, m0 = blockIdx.y * 128;
  __shared__ __align__(16) char As[128 * 128];
  __shared__ __align__(16) char Bs[128 * 128];
  int t = threadIdx.x;
  int wave = t >> 6, lane = t & 63;
  int wm = (wave >> 1) * 64, wn = (wave & 1) * 64;
  int lr = lane & 15, lg = lane >> 4;
  f32x4 acc[4][4] = {};

  for (int kt = 0; kt < D_MODEL; kt += 64) {
#pragma unroll
    for (int c = 0; c < 4; ++c) {
      int idx = t + 256 * c;
      int row = idx >> 3, ch = idx & 7;
      int cb = (ch * 16) ^ ((row & 7) << 4);
      uint4 bv = *(const uint4*)(WT + (size_t)(n0 + row) * D_MODEL + kt + ch * 8);
      *(uint4*)(Bs + row * 128 + cb) = bv;
      uint4 av;
      if (A_F32) {
        const float* A = (const float*)args.A[z];
        const float* ap = A + (size_t)(m0 + row) * D_MODEL + kt + ch * 8;
        float4 v0 = *(const float4*)ap;
        float4 v1 = *(const float4*)(ap + 4);
        av.x = (uint32)f2bf(v0.x) | ((uint32)f2bf(v0.y) << 16);
        av.y = (uint32)f2bf(v0.z) | ((uint32)f2bf(v0.w) << 16);
        av.z = (uint32)f2bf(v1.x) | ((uint32)f2bf(v1.y) << 16);
        av.w = (uint32)f2bf(v1.z) | ((uint32)f2bf(v1.w) << 16);
      } else {
        const unsigned short* A = (const unsigned short*)args.A[z];
        av = *(const uint4*)(A + (size_t)(m0 + row) * D_MODEL + kt + ch * 8);
      }
      *(uint4*)(As + row * 128 + cb) = av;
    }
    __syncthreads();
    short8 af[4][2], bf[4][2];
#pragma unroll
    for (int f = 0; f < 4; ++f) {
#pragma unroll
      for (int kk = 0; kk < 2; ++kk) {
        int ra = wm + f * 16 + lr;
        af[f][kk] = *(const short8*)(As + ra * 128 + ((kk * 64 + lg * 16) ^ ((ra & 7) << 4)));
        int rb = wn + f * 16 + lr;
        bf[f][kk] = *(const short8*)(Bs + rb * 128 + ((kk * 64 + lg * 16) ^ ((rb & 7) << 4)));
      }
    }
#pragma unroll
    for (int i = 0; i < 4; ++i)
#pragma unroll
      for (int j = 0; j < 4; ++j)
#pragma unroll
        for (int kk = 0; kk < 2; ++kk)
          acc[i][j] = __builtin_amdgcn_mfma_f32_16x16x32_bf16(af[i][kk], bf[j][kk], acc[i][j], 0, 0, 0);
    __syncthreads();
  }
#pragma unroll
  for (int i = 0; i < 4; ++i)
#pragma unroll
    for (int j = 0; j < 4; ++j) {
      int col = n0 + wn + j * 16 + lr;
      float bb = bias[col];
#pragma unroll
      for (int r = 0; r < 4; ++r) {
        int row = m0 + wm + i * 16 + lg * 4 + r;
        float v = acc[i][j][r] + bb;
        if (OUT_F32)
          ((float*)args.C[z])[(size_t)row * D_MODEL + col] = v;
        else
          ((unsigned short*)args.C[z])[(size_t)row * D_MODEL + col] = f2bf(v);
      }
    }
}

// ---------------------------------------------------------------------------
// Kernel 3: V [B*S, D] bf16 -> Vt [(b*H+h)*64 + dh][S] bf16
// ---------------------------------------------------------------------------
__global__ __launch_bounds__(256) void vt_kernel(const unsigned short* V, unsigned short* Vt) {
  int bh = blockIdx.y;
  int b = bh >> 4;
  int h = bh & 15;
  int s0 = blockIdx.x * 64;
  __shared__ unsigned short tile[64][80];
  int t = threadIdx.x;
  int r = t >> 2, c = (t & 3) * 16;
  const unsigned short* src = V + (size_t)(b * SEQ + s0 + r) * D_MODEL + h * HDIM + c;
  __align__(16) unsigned short buf[16];
  ((uint4*)buf)[0] = *(const uint4*)src;
  ((uint4*)buf)[1] = *(const uint4*)(src + 8);
#pragma unroll
  for (int j = 0; j < 16; ++j) tile[r][c + j] = buf[j];
  __syncthreads();
  __align__(16) unsigned short tmp[16];
#pragma unroll
  for (int j = 0; j < 16; ++j) tmp[j] = tile[c + j][r];
  unsigned short* dst = Vt + ((size_t)bh * HDIM + r) * SEQ + s0 + c;
  *(uint4*)dst = ((uint4*)tmp)[0];
  *(uint4*)(dst + 8) = ((uint4*)tmp)[1];
}

// ---------------------------------------------------------------------------
// Kernel 4: two-pass attention. 8 waves x 16 q-rows = q-tile 128.
//   Max-free softmax (scores bounded << 88/log2e): pass 1 accumulates
//   sum of exp2(s*c) per lane, one shuffle reduce at the end.
//   Double-buffered K/V tiles, 1 barrier per tile.
// ---------------------------------------------------------------------------
__global__ __launch_bounds__(512) void attn_kernel(const unsigned short* Q, const unsigned short* K,
                                                   const unsigned short* Vt, float* attn,
                                                   unsigned short* ctx) {
  int bh = blockIdx.y;
  int b = bh >> 4;
  int h = bh & 15;
  int q0 = blockIdx.x * 128;
  int t = threadIdx.x, wave = t >> 6, lane = t & 63;
  int lr = lane & 15, lg = lane >> 4;

  __shared__ __align__(16) char Ks[2][64 * 128];
  __shared__ __align__(16) char Vs[2][64 * 128];
  __shared__ __align__(16) char Ps[8][16 * 128];

  // staging: 512 threads x 16B = one 64x64 bf16 tile
  int srow = t >> 3, sch = t & 7;
  int scb = (sch * 16) ^ ((srow & 7) << 4);
  const unsigned short* Kp = K + (size_t)(b * SEQ) * D_MODEL + h * HDIM + sch * 8;
  const unsigned short* Vp = Vt + (size_t)bh * HDIM * SEQ + (size_t)srow * SEQ + sch * 8;

  // Q fragments (registers for the whole block)
  short8 aq[2];
  {
    int qrow = b * SEQ + q0 + wave * 16 + lr;
    aq[0] = *(const short8*)(Q + (size_t)qrow * D_MODEL + h * HDIM + lg * 8);
    aq[1] = *(const short8*)(Q + (size_t)qrow * D_MODEL + h * HDIM + 32 + lg * 8);
  }

  const float SCL = 0.125f * 1.44269504f;  // 1/sqrt(Dh) * log2(e)
  float lsum[4] = {0.f, 0.f, 0.f, 0.f};

  // ---- pass 1: row sum of exp2 ----
  {
    uint4 kv = *(const uint4*)(Kp + (size_t)srow * D_MODEL);
    *(uint4*)(Ks[0] + srow * 128 + scb) = kv;
  }
  __syncthreads();
  int cur = 0;
  for (int ti = 0; ti < 32; ++ti) {
    uint4 nk;
    bool more = (ti + 1) < 32;
    if (more) nk = *(const uint4*)(Kp + (size_t)((ti + 1) * 64 + srow) * D_MODEL);
    f32x4 st[4] = {};
#pragma unroll
    for (int n = 0; n < 4; ++n)
#pragma unroll
      for (int kk = 0; kk < 2; ++kk) {
        int kr = n * 16 + lr;
        short8 bk = *(const short8*)(Ks[cur] + kr * 128 + ((kk * 64 + lg * 16) ^ ((kr & 7) << 4)));
        st[n] = __builtin_amdgcn_mfma_f32_16x16x32_bf16(aq[kk], bk, st[n], 0, 0, 0);
      }
#pragma unroll
    for (int n = 0; n < 4; ++n)
#pragma unroll
      for (int r = 0; r < 4; ++r)
        lsum[r] += fexp2(st[n][r] * SCL);
    if (more) *(uint4*)(Ks[cur ^ 1] + srow * 128 + scb) = nk;
    __syncthreads();
    cur ^= 1;
  }
  float invl[4];
#pragma unroll
  for (int r = 0; r < 4; ++r) {
    float s = lsum[r];
    s += __shfl_xor(s, 1, 64);
    s += __shfl_xor(s, 2, 64);
    s += __shfl_xor(s, 4, 64);
    s += __shfl_xor(s, 8, 64);
    invl[r] = 1.f / s;
  }

  // ---- pass 2: recompute, write normalized attention fp32, PV ----
  f32x4 oacc[4] = {};
  float* arow = attn + (size_t)bh * SEQ * SEQ + ((size_t)q0 + wave * 16 + lg * 4) * SEQ + lr;
  {
    uint4 kv = *(const uint4*)(Kp + (size_t)srow * D_MODEL);
    *(uint4*)(Ks[0] + srow * 128 + scb) = kv;
    uint4 vv = *(const uint4*)Vp;
    *(uint4*)(Vs[0] + srow * 128 + scb) = vv;
  }
  __syncthreads();
  cur = 0;
  for (int ti = 0; ti < 32; ++ti) {
    uint4 nk, nv;
    bool more = (ti + 1) < 32;
    if (more) {
      nk = *(const uint4*)(Kp + (size_t)((ti + 1) * 64 + srow) * D_MODEL);
      nv = *(const uint4*)(Vp + (ti + 1) * 64);
    }
    f32x4 st[4] = {};
#pragma unroll
    for (int n = 0; n < 4; ++n)
#pragma unroll
      for (int kk = 0; kk < 2; ++kk) {
        int kr = n * 16 + lr;
        short8 bk = *(const short8*)(Ks[cur] + kr * 128 + ((kk * 64 + lg * 16) ^ ((kr & 7) << 4)));
        st[n] = __builtin_amdgcn_mfma_f32_16x16x32_bf16(aq[kk], bk, st[n], 0, 0, 0);
      }
    char* psw = Ps[wave];
#pragma unroll
    for (int n = 0; n < 4; ++n)
#pragma unroll
      for (int r = 0; r < 4; ++r) {
        float p = fexp2(st[n][r] * SCL) * invl[r];
        arow[(size_t)r * SEQ + ti * 64 + n * 16] = p;
        int prow = lg * 4 + r;
        *(unsigned short*)(psw + prow * 128 + ((n * 32 + lr * 2) ^ ((prow & 7) << 4))) = f2bf(p);
      }
    // PV: A = P (16 x 64) from wave-local LDS, B = V tile
    short8 ap[2];
#pragma unroll
    for (int kk = 0; kk < 2; ++kk)
      ap[kk] = *(const short8*)(psw + lr * 128 + ((kk * 64 + lg * 16) ^ ((lr & 7) << 4)));
#pragma unroll
    for (int n2 = 0; n2 < 4; ++n2)
#pragma unroll
      for (int kk = 0; kk < 2; ++kk) {
        int vr = n2 * 16 + lr;
        short8 bv = *(const short8*)(Vs[cur] + vr * 128 + ((kk * 64 + lg * 16) ^ ((vr & 7) << 4)));
        oacc[n2] = __builtin_amdgcn_mfma_f32_16x16x32_bf16(ap[kk], bv, oacc[n2], 0, 0, 0);
      }
    if (more) {
      *(uint4*)(Ks[cur ^ 1] + srow * 128 + scb) = nk;
      *(uint4*)(Vs[cur ^ 1] + srow * 128 + scb) = nv;
    }
    __syncthreads();
    cur ^= 1;
  }
#pragma unroll
  for (int n2 = 0; n2 < 4; ++n2)
#pragma unroll
    for (int r = 0; r < 4; ++r) {
      int row = b * SEQ + q0 + wave * 16 + lg * 4 + r;
      ctx[(size_t)row * D_MODEL + h * HDIM + n2 * 16 + lr] = f2bf(oacc[n2][r]);
    }
}

// ---------------------------------------------------------------------------
extern "C" void kernel_launch(void* const* d_in, const int* in_sizes, int n_in,
                              void* d_out, int out_size, void* d_ws, size_t ws_size,
                              hipStream_t stream) {
  const float* query = (const float*)d_in[0];
  const float* key   = (const float*)d_in[1];
  const float* value = (const float*)d_in[2];
  const float* Wq = (const float*)d_in[3];
  const float* bq = (const float*)d_in[4];
  const float* Wk = (const float*)d_in[5];
  const float* bk = (const float*)d_in[6];
  const float* Wv = (const float*)d_in[7];
  const float* bv = (const float*)d_in[8];
  const float* Wo = (const float*)d_in[9];
  const float* bo = (const float*)d_in[10];

  char* ws = (char*)d_ws;
  const size_t MB = (size_t)1 << 20;
  unsigned short* WqT = (unsigned short*)(ws + 0 * MB);
  unsigned short* WkT = (unsigned short*)(ws + 2 * MB);
  unsigned short* WvT = (unsigned short*)(ws + 4 * MB);
  unsigned short* WoT = (unsigned short*)(ws + 6 * MB);
  unsigned short* Qw  = (unsigned short*)(ws + 8 * MB);
  unsigned short* Kw  = (unsigned short*)(ws + 16 * MB);
  unsigned short* Vw  = (unsigned short*)(ws + 24 * MB);
  unsigned short* Vtw = (unsigned short*)(ws + 32 * MB);
  unsigned short* Cw  = (unsigned short*)(ws + 40 * MB);

  float* out0 = (float*)d_out;
  float* attn = out0 + (size_t)MROWS * D_MODEL;

  // 1. weight transpose + bf16 convert
  WtArgs wa;
  wa.src[0] = Wq; wa.src[1] = Wk; wa.src[2] = Wv; wa.src[3] = Wo;
  wt_kernel<<<dim3(16, 16, 4), 256, 0, stream>>>(wa, WqT);

  // 2. QKV projections (batched over z)
  GemmArgs ga;
  ga.A[0] = query; ga.A[1] = key; ga.A[2] = value;
  ga.W[0] = WqT; ga.W[1] = WkT; ga.W[2] = WvT;
  ga.bias[0] = bq; ga.bias[1] = bk; ga.bias[2] = bv;
  ga.C[0] = Qw; ga.C[1] = Kw; ga.C[2] = Vw;
  gemm_kernel<true, false><<<dim3(8, 32, 3), 256, 0, stream>>>(ga);

  // 3. V transpose per (b,h)
  vt_kernel<<<dim3(32, 32), 256, 0, stream>>>(Vw, Vtw);

  // 4. attention (writes attention matrix fp32 + context bf16)
  attn_kernel<<<dim3(16, 32), 512, 0, stream>>>(Qw, Kw, Vtw, attn, Cw);

  // 5. output projection -> fp32 d_out
  GemmArgs go;
  go.A[0] = Cw; go.A[1] = Cw; go.A[2] = Cw;
  go.W[0] = WoT; go.W[1] = WoT; go.W[2] = WoT;
  go.bias[0] = bo; go.bias[1] = bo; go.bias[2] = bo;
  go.C[0] = d_out; go.C[1] = d_out; go.C[2] = d_out;
  gemm_kernel<false, true><<<dim3(8, 32, 1), 256, 0, stream>>>(go);
}

// Round 4
// 326.839 us; speedup vs baseline: 1.4259x; 1.0261x over previous
//
#include <hip/hip_runtime.h>
#include <math.h>

#define D_MODEL 1024
#define NHEADS 16
#define HDIM 64
#define BATCH 2
#define SEQ 2048
#define MROWS (BATCH * SEQ)  // 4096

typedef unsigned int uint32;
typedef __attribute__((ext_vector_type(8))) short short8;
typedef __attribute__((ext_vector_type(4))) float f32x4;
typedef __attribute__((ext_vector_type(16))) float f32x16;
typedef __attribute__((ext_vector_type(2))) unsigned int uint2v;

__device__ __forceinline__ unsigned short f2bf(float f) {
  unsigned int u = __float_as_uint(f);
  u += 0x7fffu + ((u >> 16) & 1u);
  return (unsigned short)(u >> 16);
}

__device__ __forceinline__ float fexp2(float x) {
  float r;
  asm("v_exp_f32 %0, %1" : "=v"(r) : "v"(x));
  return r;
}

__device__ __forceinline__ unsigned int cvtpk(float lo, float hi) {
  unsigned int r;
  asm("v_cvt_pk_bf16_f32 %0, %1, %2" : "=v"(r) : "v"(lo), "v"(hi));
  return r;
}

// ---------------------------------------------------------------------------
// Kernel 1: convert 4 weights fp32 [K][N] -> bf16 transposed [N][K]
// ---------------------------------------------------------------------------
struct WtArgs { const float* src[4]; };

__global__ __launch_bounds__(256) void wt_kernel(WtArgs args, unsigned short* dst) {
  const float* W = args.src[blockIdx.z];
  unsigned short* WT = dst + (size_t)blockIdx.z * (D_MODEL * D_MODEL);
  __shared__ unsigned short tile[64][80];
  int t = threadIdx.x;
  int r = t >> 2, cc = (t & 3) * 16;
  int k0 = blockIdx.y * 64, n0 = blockIdx.x * 64;
  const float* src = W + (size_t)(k0 + r) * D_MODEL + n0 + cc;
#pragma unroll
  for (int j = 0; j < 16; j += 4) {
    float4 v = *(const float4*)(src + j);
    tile[r][cc + j + 0] = f2bf(v.x);
    tile[r][cc + j + 1] = f2bf(v.y);
    tile[r][cc + j + 2] = f2bf(v.z);
    tile[r][cc + j + 3] = f2bf(v.w);
  }
  __syncthreads();
  __align__(16) unsigned short tmp[16];
#pragma unroll
  for (int j = 0; j < 16; ++j) tmp[j] = tile[cc + j][r];
  unsigned short* d = WT + (size_t)(n0 + r) * D_MODEL + k0 + cc;
  *(uint4*)d = ((uint4*)tmp)[0];
  *(uint4*)(d + 8) = ((uint4*)tmp)[1];
}

// ---------------------------------------------------------------------------
// Kernel 2/5: GEMM  C[M,N] = A[M,K] * WT[N,K]^T + bias
// ---------------------------------------------------------------------------
struct GemmArgs {
  const void* A[3];
  const unsigned short* W[3];
  const float* bias[3];
  void* C[3];
};

template <bool A_F32, bool OUT_F32>
__global__ __launch_bounds__(256) void gemm_kernel(GemmArgs args) {
  int z = blockIdx.z;
  const unsigned short* WT = args.W[z];
  const float* bias = args.bias[z];
  int n0 = blockIdx.x * 128, m0 = blockIdx.y * 128;
  __shared__ __align__(16) char As[128 * 128];
  __shared__ __align__(16) char Bs[128 * 128];
  int t = threadIdx.x;
  int wave = t >> 6, lane = t & 63;
  int wm = (wave >> 1) * 64, wn = (wave & 1) * 64;
  int lr = lane & 15, lg = lane >> 4;
  f32x4 acc[4][4] = {};

  for (int kt = 0; kt < D_MODEL; kt += 64) {
#pragma unroll
    for (int c = 0; c < 4; ++c) {
      int idx = t + 256 * c;
      int row = idx >> 3, ch = idx & 7;
      int cb = (ch * 16) ^ ((row & 7) << 4);
      uint4 bv = *(const uint4*)(WT + (size_t)(n0 + row) * D_MODEL + kt + ch * 8);
      *(uint4*)(Bs + row * 128 + cb) = bv;
      uint4 av;
      if (A_F32) {
        const float* A = (const float*)args.A[z];
        const float* ap = A + (size_t)(m0 + row) * D_MODEL + kt + ch * 8;
        float4 v0 = *(const float4*)ap;
        float4 v1 = *(const float4*)(ap + 4);
        av.x = (uint32)f2bf(v0.x) | ((uint32)f2bf(v0.y) << 16);
        av.y = (uint32)f2bf(v0.z) | ((uint32)f2bf(v0.w) << 16);
        av.z = (uint32)f2bf(v1.x) | ((uint32)f2bf(v1.y) << 16);
        av.w = (uint32)f2bf(v1.z) | ((uint32)f2bf(v1.w) << 16);
      } else {
        const unsigned short* A = (const unsigned short*)args.A[z];
        av = *(const uint4*)(A + (size_t)(m0 + row) * D_MODEL + kt + ch * 8);
      }
      *(uint4*)(As + row * 128 + cb) = av;
    }
    __syncthreads();
    short8 af[4][2], bf[4][2];
#pragma unroll
    for (int f = 0; f < 4; ++f) {
#pragma unroll
      for (int kk = 0; kk < 2; ++kk) {
        int ra = wm + f * 16 + lr;
        af[f][kk] = *(const short8*)(As + ra * 128 + ((kk * 64 + lg * 16) ^ ((ra & 7) << 4)));
        int rb = wn + f * 16 + lr;
        bf[f][kk] = *(const short8*)(Bs + rb * 128 + ((kk * 64 + lg * 16) ^ ((rb & 7) << 4)));
      }
    }
#pragma unroll
    for (int i = 0; i < 4; ++i)
#pragma unroll
      for (int j = 0; j < 4; ++j)
#pragma unroll
        for (int kk = 0; kk < 2; ++kk)
          acc[i][j] = __builtin_amdgcn_mfma_f32_16x16x32_bf16(af[i][kk], bf[j][kk], acc[i][j], 0, 0, 0);
    __syncthreads();
  }
#pragma unroll
  for (int i = 0; i < 4; ++i)
#pragma unroll
    for (int j = 0; j < 4; ++j) {
      int col = n0 + wn + j * 16 + lr;
      float bb = bias[col];
#pragma unroll
      for (int r = 0; r < 4; ++r) {
        int row = m0 + wm + i * 16 + lg * 4 + r;
        float v = acc[i][j][r] + bb;
        if (OUT_F32)
          ((float*)args.C[z])[(size_t)row * D_MODEL + col] = v;
        else
          ((unsigned short*)args.C[z])[(size_t)row * D_MODEL + col] = f2bf(v);
      }
    }
}

// ---------------------------------------------------------------------------
// Kernel 3: V [B*S, D] bf16 -> Vt [(b*H+h)*64 + dh][S] bf16
// ---------------------------------------------------------------------------
__global__ __launch_bounds__(256) void vt_kernel(const unsigned short* V, unsigned short* Vt) {
  int bh = blockIdx.y;
  int b = bh >> 4;
  int h = bh & 15;
  int s0 = blockIdx.x * 64;
  __shared__ unsigned short tile[64][80];
  int t = threadIdx.x;
  int r = t >> 2, c = (t & 3) * 16;
  const unsigned short* src = V + (size_t)(b * SEQ + s0 + r) * D_MODEL + h * HDIM + c;
  __align__(16) unsigned short buf[16];
  ((uint4*)buf)[0] = *(const uint4*)src;
  ((uint4*)buf)[1] = *(const uint4*)(src + 8);
#pragma unroll
  for (int j = 0; j < 16; ++j) tile[r][c + j] = buf[j];
  __syncthreads();
  __align__(16) unsigned short tmp[16];
#pragma unroll
  for (int j = 0; j < 16; ++j) tmp[j] = tile[c + j][r];
  unsigned short* dst = Vt + ((size_t)bh * HDIM + r) * SEQ + s0 + c;
  *(uint4*)dst = ((uint4*)tmp)[0];
  *(uint4*)(dst + 8) = ((uint4*)tmp)[1];
}

// ---------------------------------------------------------------------------
// Kernel 4a: attn_ctx — swapped QK^T (32x32x16), T12 in-register P transpose,
//   unnormalized PV, row-sum -> invl + ctx. 4 waves x 32 q = 128-q blocks.
//
//   P-register map (per lane, q = lane&31, hi = lane>>5):
//     P0[n][j2] = pack_bf16(k = n*32 + 8*j2 + 4*hi + {0,1})
//     P1[n][j2] = pack_bf16(k = n*32 + 8*j2 + 4*hi + {2,3})
//   PV A-fragment kkblk (n = kkblk>>1, c = kkblk&1) needs lane-element e:
//     k = kkblk*16 + hi*8 + e. With permlane32_swap semantics
//     (x: lo=own a, hi=partner b; y: lo=partner a, hi=own b):
//     s0 = swap(P0[n][2c], P0[n][2c+1]) -> word0 = s0.x, word2 = s0.y
//     s1 = swap(P1[n][2c], P1[n][2c+1]) -> word1 = s1.x, word3 = s1.y
// ---------------------------------------------------------------------------
__global__ __launch_bounds__(256) void attn_ctx_kernel(const unsigned short* Q, const unsigned short* K,
                                                       const unsigned short* Vt, float* invl_g,
                                                       unsigned short* ctx) {
  int bh = blockIdx.y, b = bh >> 4, h = bh & 15;
  int q0 = blockIdx.x * 128;
  int t = threadIdx.x, wave = t >> 6, lane = t & 63;
  int l31 = lane & 31, hi = lane >> 5;

  __shared__ __align__(16) char Ks[2][64 * 128];
  __shared__ __align__(16) char Vs[2][64 * 128];

  const unsigned short* Kp = K + (size_t)(b * SEQ) * D_MODEL + h * HDIM;
  const unsigned short* Vp = Vt + (size_t)bh * HDIM * SEQ;

  // B-operand: Q^T fragments (col = q = lane&31, k-dim = d)
  short8 bq[4];
  {
    const unsigned short* qp = Q + (size_t)(b * SEQ + q0 + wave * 32 + l31) * D_MODEL + h * HDIM + hi * 8;
#pragma unroll
    for (int kk = 0; kk < 4; ++kk) bq[kk] = *(const short8*)(qp + kk * 16);
  }

  const float SCL = 0.125f * 1.44269504f;
  float lsum = 0.f;
  f32x16 oacc[2] = {};

#pragma unroll
  for (int c = 0; c < 2; ++c) {
    int idx = t + 256 * c;
    int row = idx >> 3, ch = idx & 7;
    int cb = (ch * 16) ^ ((row & 7) << 4);
    *(uint4*)(Ks[0] + row * 128 + cb) = *(const uint4*)(Kp + (size_t)row * D_MODEL + ch * 8);
    *(uint4*)(Vs[0] + row * 128 + cb) = *(const uint4*)(Vp + (size_t)row * SEQ + ch * 8);
  }
  __syncthreads();
  int cur = 0;
  for (int ti = 0; ti < 32; ++ti) {
    uint4 nk[2], nv[2];
    bool more = (ti + 1) < 32;
    if (more) {
#pragma unroll
      for (int c = 0; c < 2; ++c) {
        int idx = t + 256 * c;
        int row = idx >> 3, ch = idx & 7;
        nk[c] = *(const uint4*)(Kp + (size_t)((ti + 1) * 64 + row) * D_MODEL + ch * 8);
        nv[c] = *(const uint4*)(Vp + (size_t)row * SEQ + (ti + 1) * 64 + ch * 8);
      }
    }
    // QK^T swapped: D[k][q], A = K tile, B = Q^T
    f32x16 st[2] = {};
#pragma unroll
    for (int n = 0; n < 2; ++n)
#pragma unroll
      for (int kk = 0; kk < 4; ++kk) {
        int kr = n * 32 + l31;
        short8 ak = *(const short8*)(Ks[cur] + kr * 128 + ((kk * 32 + hi * 16) ^ ((kr & 7) << 4)));
        st[n] = __builtin_amdgcn_mfma_f32_32x32x16_bf16(ak, bq[kk], st[n], 0, 0, 0);
      }
    // exp2, row-sum, pack to bf16 pairs
    unsigned int P0[2][4], P1[2][4];
#pragma unroll
    for (int n = 0; n < 2; ++n)
#pragma unroll
      for (int j2 = 0; j2 < 4; ++j2) {
        float p0 = fexp2(st[n][4 * j2 + 0] * SCL);
        float p1 = fexp2(st[n][4 * j2 + 1] * SCL);
        float p2 = fexp2(st[n][4 * j2 + 2] * SCL);
        float p3 = fexp2(st[n][4 * j2 + 3] * SCL);
        lsum += (p0 + p1) + (p2 + p3);
        P0[n][j2] = cvtpk(p0, p1);
        P1[n][j2] = cvtpk(p2, p3);
      }
    // permlane32_swap -> A-fragments of P (row = q = lane&31, k contiguous)
    short8 pa[4];
#pragma unroll
    for (int n = 0; n < 2; ++n)
#pragma unroll
      for (int c = 0; c < 2; ++c) {
        uint2v s0 = __builtin_amdgcn_permlane32_swap(P0[n][2 * c], P0[n][2 * c + 1], false, false);
        uint2v s1 = __builtin_amdgcn_permlane32_swap(P1[n][2 * c], P1[n][2 * c + 1], false, false);
        uint4 w;
        w.x = s0.x; w.y = s1.x; w.z = s0.y; w.w = s1.y;
        pa[n * 2 + c] = *(short8*)&w;
      }
    // PV: D[q][dv] += P[q][k] * V[k][dv]
#pragma unroll
    for (int n2 = 0; n2 < 2; ++n2)
#pragma unroll
      for (int kk = 0; kk < 4; ++kk) {
        int vr = n2 * 32 + l31;
        short8 bv = *(const short8*)(Vs[cur] + vr * 128 + ((kk * 32 + hi * 16) ^ ((vr & 7) << 4)));
        oacc[n2] = __builtin_amdgcn_mfma_f32_32x32x16_bf16(pa[kk], bv, oacc[n2], 0, 0, 0);
      }
    if (more) {
#pragma unroll
      for (int c = 0; c < 2; ++c) {
        int idx = t + 256 * c;
        int row = idx >> 3, ch = idx & 7;
        int cb = (ch * 16) ^ ((row & 7) << 4);
        *(uint4*)(Ks[cur ^ 1] + row * 128 + cb) = nk[c];
        *(uint4*)(Vs[cur ^ 1] + row * 128 + cb) = nv[c];
      }
    }
    __syncthreads();
    cur ^= 1;
  }
  float tot = lsum + __shfl_xor(lsum, 32, 64);
  float inv = 1.f / tot;
  if (lane < 32) invl_g[(size_t)bh * SEQ + q0 + wave * 32 + l31] = inv;
  float iv16[16];
#pragma unroll
  for (int reg = 0; reg < 16; ++reg) {
    int qr = (reg & 3) + 8 * (reg >> 2) + 4 * hi;
    iv16[reg] = __shfl(inv, qr, 64);
  }
#pragma unroll
  for (int n2 = 0; n2 < 2; ++n2)
#pragma unroll
    for (int reg = 0; reg < 16; ++reg) {
      int qr = (reg & 3) + 8 * (reg >> 2) + 4 * hi;
      int row = b * SEQ + q0 + wave * 32 + qr;
      ctx[(size_t)row * D_MODEL + h * HDIM + n2 * 32 + l31] = f2bf(oacc[n2][reg] * iv16[reg]);
    }
}

// ---------------------------------------------------------------------------
// Kernel 4b: attn_w — recompute QK^T (32x32x16), normalize, nontemporal
//   fp32 stores of the attention matrix. 4 waves x 32 q = 128-q blocks.
// ---------------------------------------------------------------------------
__global__ __launch_bounds__(256) void attn_w_kernel(const unsigned short* Q, const unsigned short* K,
                                                     const float* invl_g, float* attn) {
  int bh = blockIdx.y, b = bh >> 4, h = bh & 15;
  int q0 = blockIdx.x * 128;
  int t = threadIdx.x, wave = t >> 6, lane = t & 63;
  int l31 = lane & 31, hi = lane >> 5;
  __shared__ __align__(16) char Ks[2][64 * 128];

  const unsigned short* Kp = K + (size_t)(b * SEQ) * D_MODEL + h * HDIM;
  // A-operand: Q fragments (row = q = lane&31)
  short8 aq[4];
  {
    const unsigned short* qp = Q + (size_t)(b * SEQ + q0 + wave * 32 + l31) * D_MODEL + h * HDIM + hi * 8;
#pragma unroll
    for (int kk = 0; kk < 4; ++kk) aq[kk] = *(const short8*)(qp + kk * 16);
  }
  float4 invl4[4];
#pragma unroll
  for (int j2 = 0; j2 < 4; ++j2)
    invl4[j2] = *(const float4*)(invl_g + (size_t)bh * SEQ + q0 + wave * 32 + 8 * j2 + 4 * hi);

  // per-reg row pointers (16 rows this lane touches)
  float* rowp[16];
  {
    float* abase = attn + (size_t)bh * SEQ * SEQ + l31;
#pragma unroll
    for (int reg = 0; reg < 16; ++reg) {
      int qr = (reg & 3) + 8 * (reg >> 2) + 4 * hi;
      rowp[reg] = abase + (size_t)(q0 + wave * 32 + qr) * SEQ;
    }
  }
  const float SCL = 0.125f * 1.44269504f;

#pragma unroll
  for (int c = 0; c < 2; ++c) {
    int idx = t + 256 * c;
    int row = idx >> 3, ch = idx & 7;
    int cb = (ch * 16) ^ ((row & 7) << 4);
    *(uint4*)(Ks[0] + row * 128 + cb) = *(const uint4*)(Kp + (size_t)row * D_MODEL + ch * 8);
  }
  __syncthreads();
  int cur = 0;
  for (int ti = 0; ti < 32; ++ti) {
    uint4 nk[2];
    bool more = (ti + 1) < 32;
    if (more) {
#pragma unroll
      for (int c = 0; c < 2; ++c) {
        int idx = t + 256 * c;
        int row = idx >> 3, ch = idx & 7;
        nk[c] = *(const uint4*)(Kp + (size_t)((ti + 1) * 64 + row) * D_MODEL + ch * 8);
      }
    }
    f32x16 st[2] = {};
#pragma unroll
    for (int n = 0; n < 2; ++n)
#pragma unroll
      for (int kk = 0; kk < 4; ++kk) {
        int kr = n * 32 + l31;
        short8 bk = *(const short8*)(Ks[cur] + kr * 128 + ((kk * 32 + hi * 16) ^ ((kr & 7) << 4)));
        st[n] = __builtin_amdgcn_mfma_f32_32x32x16_bf16(aq[kk], bk, st[n], 0, 0, 0);
      }
#pragma unroll
    for (int n = 0; n < 2; ++n)
#pragma unroll
      for (int reg = 0; reg < 16; ++reg) {
        float p = fexp2(st[n][reg] * SCL) * invl4[reg >> 2][reg & 3];
        __builtin_nontemporal_store(p, rowp[reg] + ti * 64 + n * 32);
      }
    if (more) {
#pragma unroll
      for (int c = 0; c < 2; ++c) {
        int idx = t + 256 * c;
        int row = idx >> 3, ch = idx & 7;
        int cb = (ch * 16) ^ ((row & 7) << 4);
        *(uint4*)(Ks[cur ^ 1] + row * 128 + cb) = nk[c];
      }
    }
    __syncthreads();
    cur ^= 1;
  }
}

// ---------------------------------------------------------------------------
extern "C" void kernel_launch(void* const* d_in, const int* in_sizes, int n_in,
                              void* d_out, int out_size, void* d_ws, size_t ws_size,
                              hipStream_t stream) {
  const float* query = (const float*)d_in[0];
  const float* key   = (const float*)d_in[1];
  const float* value = (const float*)d_in[2];
  const float* Wq = (const float*)d_in[3];
  const float* bq = (const float*)d_in[4];
  const float* Wk = (const float*)d_in[5];
  const float* bk = (const float*)d_in[6];
  const float* Wv = (const float*)d_in[7];
  const float* bv = (const float*)d_in[8];
  const float* Wo = (const float*)d_in[9];
  const float* bo = (const float*)d_in[10];

  char* ws = (char*)d_ws;
  const size_t MB = (size_t)1 << 20;
  unsigned short* WqT = (unsigned short*)(ws + 0 * MB);
  unsigned short* WkT = (unsigned short*)(ws + 2 * MB);
  unsigned short* WvT = (unsigned short*)(ws + 4 * MB);
  unsigned short* WoT = (unsigned short*)(ws + 6 * MB);
  unsigned short* Qw  = (unsigned short*)(ws + 8 * MB);
  unsigned short* Kw  = (unsigned short*)(ws + 16 * MB);
  unsigned short* Vw  = (unsigned short*)(ws + 24 * MB);
  unsigned short* Vtw = (unsigned short*)(ws + 32 * MB);
  unsigned short* Cw  = (unsigned short*)(ws + 40 * MB);
  float* invl_g       = (float*)(ws + 48 * MB);

  float* out0 = (float*)d_out;
  float* attn = out0 + (size_t)MROWS * D_MODEL;

  WtArgs wa;
  wa.src[0] = Wq; wa.src[1] = Wk; wa.src[2] = Wv; wa.src[3] = Wo;
  wt_kernel<<<dim3(16, 16, 4), 256, 0, stream>>>(wa, WqT);

  GemmArgs ga;
  ga.A[0] = query; ga.A[1] = key; ga.A[2] = value;
  ga.W[0] = WqT; ga.W[1] = WkT; ga.W[2] = WvT;
  ga.bias[0] = bq; ga.bias[1] = bk; ga.bias[2] = bv;
  ga.C[0] = Qw; ga.C[1] = Kw; ga.C[2] = Vw;
  gemm_kernel<true, false><<<dim3(8, 32, 3), 256, 0, stream>>>(ga);

  vt_kernel<<<dim3(32, 32), 256, 0, stream>>>(Vw, Vtw);

  attn_ctx_kernel<<<dim3(16, 32), 256, 0, stream>>>(Qw, Kw, Vtw, invl_g, Cw);
  attn_w_kernel<<<dim3(16, 32), 256, 0, stream>>>(Qw, Kw, invl_g, attn);

  GemmArgs go;
  go.A[0] = Cw; go.A[1] = Cw; go.A[2] = Cw;
  go.W[0] = WoT; go.W[1] = WoT; go.W[2] = WoT;
  go.bias[0] = bo; go.bias[1] = bo; go.bias[2] = bo;
  go.C[0] = d_out; go.C[1] = d_out; go.C[2] = d_out;
  gemm_kernel<false, true><<<dim3(8, 32, 1), 256, 0, stream>>>(go);
}

// Round 5
// 297.028 us; speedup vs baseline: 1.5690x; 1.1004x over previous
//
#include <hip/hip_runtime.h>
#include <math.h>

#define D_MODEL 1024
#define NHEADS 16
#define HDIM 64
#define BATCH 2
#define SEQ 2048
#define MROWS (BATCH * SEQ)  // 4096

typedef unsigned int uint32;
typedef __attribute__((ext_vector_type(8))) short short8;
typedef __attribute__((ext_vector_type(4))) float f32x4;
typedef __attribute__((ext_vector_type(16))) float f32x16;
typedef __attribute__((ext_vector_type(2))) unsigned int uint2v;

__device__ __forceinline__ unsigned short f2bf(float f) {
  unsigned int u = __float_as_uint(f);
  u += 0x7fffu + ((u >> 16) & 1u);
  return (unsigned short)(u >> 16);
}

__device__ __forceinline__ float fexp2(float x) {
  float r;
  asm("v_exp_f32 %0, %1" : "=v"(r) : "v"(x));
  return r;
}

__device__ __forceinline__ unsigned int cvtpk(float lo, float hi) {
  unsigned int r;
  asm("v_cvt_pk_bf16_f32 %0, %1, %2" : "=v"(r) : "v"(lo), "v"(hi));
  return r;
}

__device__ __forceinline__ void gl_lds16(const void* g, void* l) {
  __builtin_amdgcn_global_load_lds((const __attribute__((address_space(1))) void*)g,
                                   (__attribute__((address_space(3))) void*)l, 16, 0, 0);
}

// ---------------------------------------------------------------------------
// Kernel 0: convert activations fp32 -> bf16 (query/key/value)
// ---------------------------------------------------------------------------
__global__ __launch_bounds__(256) void conv_kernel(const float* q, const float* k, const float* v,
                                                   unsigned short* xq, unsigned short* xk,
                                                   unsigned short* xv) {
  int z = blockIdx.y;
  const float* s = (z == 0) ? q : ((z == 1) ? k : v);
  unsigned short* d = (z == 0) ? xq : ((z == 1) ? xk : xv);
  int i = (blockIdx.x * 256 + threadIdx.x) * 8;
  float4 v0 = *(const float4*)(s + i);
  float4 v1 = *(const float4*)(s + i + 4);
  uint4 o;
  o.x = cvtpk(v0.x, v0.y);
  o.y = cvtpk(v0.z, v0.w);
  o.z = cvtpk(v1.x, v1.y);
  o.w = cvtpk(v1.z, v1.w);
  *(uint4*)(d + i) = o;
}

// ---------------------------------------------------------------------------
// Kernel 1: convert 4 weights fp32 [K][N] -> bf16 transposed [N][K]
// ---------------------------------------------------------------------------
struct WtArgs { const float* src[4]; };

__global__ __launch_bounds__(256) void wt_kernel(WtArgs args, unsigned short* dst) {
  const float* W = args.src[blockIdx.z];
  unsigned short* WT = dst + (size_t)blockIdx.z * (D_MODEL * D_MODEL);
  __shared__ unsigned short tile[64][80];
  int t = threadIdx.x;
  int r = t >> 2, cc = (t & 3) * 16;
  int k0 = blockIdx.y * 64, n0 = blockIdx.x * 64;
  const float* src = W + (size_t)(k0 + r) * D_MODEL + n0 + cc;
#pragma unroll
  for (int j = 0; j < 16; j += 4) {
    float4 v = *(const float4*)(src + j);
    tile[r][cc + j + 0] = f2bf(v.x);
    tile[r][cc + j + 1] = f2bf(v.y);
    tile[r][cc + j + 2] = f2bf(v.z);
    tile[r][cc + j + 3] = f2bf(v.w);
  }
  __syncthreads();
  __align__(16) unsigned short tmp[16];
#pragma unroll
  for (int j = 0; j < 16; ++j) tmp[j] = tile[cc + j][r];
  unsigned short* d = WT + (size_t)(n0 + r) * D_MODEL + k0 + cc;
  *(uint4*)d = ((uint4*)tmp)[0];
  *(uint4*)(d + 8) = ((uint4*)tmp)[1];
}

// ---------------------------------------------------------------------------
// Kernel 2/5: GEMM (m97 structure)  C[M,N] = A[M,K] * WT[N,K]^T + bias
//   128x128 tile, BK=64, global_load_lds width-16, LINEAR LDS, 4 waves.
// ---------------------------------------------------------------------------
struct GemmArgs {
  const unsigned short* A[3];
  const unsigned short* W[3];
  const float* bias[3];
  void* C[3];
};

template <bool OUT_F32>
__global__ __launch_bounds__(256) void gemm_kernel(GemmArgs args) {
  int z = blockIdx.z;
  const unsigned short* A = args.A[z];
  const unsigned short* WT = args.W[z];
  const float* bias = args.bias[z];
  int n0 = blockIdx.x * 128, m0 = blockIdx.y * 128;
  __shared__ __align__(16) unsigned short As[128 * 64];
  __shared__ __align__(16) unsigned short Bs[128 * 64];
  int t = threadIdx.x;
  int wave = t >> 6, lane = t & 63;
  int wm = (wave >> 1) * 64, wn = (wave & 1) * 64;
  int lr = lane & 15, lg = lane >> 4;
  int r8 = lane >> 3, c8 = (lane & 7) * 8;
  f32x4 acc[4][4] = {};

  for (int kt = 0; kt < D_MODEL; kt += 64) {
#pragma unroll
    for (int i = 0; i < 4; ++i) {
      int row = wave * 32 + i * 8;
      gl_lds16(A + (size_t)(m0 + row + r8) * D_MODEL + kt + c8, As + row * 64);
      gl_lds16(WT + (size_t)(n0 + row + r8) * D_MODEL + kt + c8, Bs + row * 64);
    }
    __syncthreads();
    short8 af[4][2], bf[4][2];
#pragma unroll
    for (int f = 0; f < 4; ++f) {
#pragma unroll
      for (int kk = 0; kk < 2; ++kk) {
        af[f][kk] = *(const short8*)((const char*)As + (wm + f * 16 + lr) * 128 + kk * 64 + lg * 16);
        bf[f][kk] = *(const short8*)((const char*)Bs + (wn + f * 16 + lr) * 128 + kk * 64 + lg * 16);
      }
    }
#pragma unroll
    for (int i = 0; i < 4; ++i)
#pragma unroll
      for (int j = 0; j < 4; ++j)
#pragma unroll
        for (int kk = 0; kk < 2; ++kk)
          acc[i][j] = __builtin_amdgcn_mfma_f32_16x16x32_bf16(af[i][kk], bf[j][kk], acc[i][j], 0, 0, 0);
    __syncthreads();
  }
#pragma unroll
  for (int i = 0; i < 4; ++i)
#pragma unroll
    for (int j = 0; j < 4; ++j) {
      int col = n0 + wn + j * 16 + lr;
      float bb = bias[col];
#pragma unroll
      for (int r = 0; r < 4; ++r) {
        int row = m0 + wm + i * 16 + lg * 4 + r;
        float v = acc[i][j][r] + bb;
        if (OUT_F32)
          ((float*)args.C[z])[(size_t)row * D_MODEL + col] = v;
        else
          ((unsigned short*)args.C[z])[(size_t)row * D_MODEL + col] = f2bf(v);
      }
    }
}

// ---------------------------------------------------------------------------
// Kernel 3: V [B*S, D] bf16 -> Vt [(b*H+h)*64 + dh][S] bf16
// ---------------------------------------------------------------------------
__global__ __launch_bounds__(256) void vt_kernel(const unsigned short* V, unsigned short* Vt) {
  int bh = blockIdx.y;
  int b = bh >> 4;
  int h = bh & 15;
  int s0 = blockIdx.x * 64;
  __shared__ unsigned short tile[64][80];
  int t = threadIdx.x;
  int r = t >> 2, c = (t & 3) * 16;
  const unsigned short* src = V + (size_t)(b * SEQ + s0 + r) * D_MODEL + h * HDIM + c;
  __align__(16) unsigned short buf[16];
  ((uint4*)buf)[0] = *(const uint4*)src;
  ((uint4*)buf)[1] = *(const uint4*)(src + 8);
#pragma unroll
  for (int j = 0; j < 16; ++j) tile[r][c + j] = buf[j];
  __syncthreads();
  __align__(16) unsigned short tmp[16];
#pragma unroll
  for (int j = 0; j < 16; ++j) tmp[j] = tile[c + j][r];
  unsigned short* dst = Vt + ((size_t)bh * HDIM + r) * SEQ + s0 + c;
  *(uint4*)dst = ((uint4*)tmp)[0];
  *(uint4*)(dst + 8) = ((uint4*)tmp)[1];
}

// ---------------------------------------------------------------------------
// Kernel 4: fused attention. Pass A: swapped QK^T (32x32x16) + exp2 + lsum
//   + T12 permlane P transpose + PV -> ctx (normalized at end).
//   Pass B: unswapped QK^T recompute + normalized nontemporal fp32 stores.
//   Q fragments are shared (swapped-B layout == unswapped-A layout).
// ---------------------------------------------------------------------------
__global__ __launch_bounds__(256) void attn_kernel(const unsigned short* Q, const unsigned short* K,
                                                   const unsigned short* Vt, float* attn,
                                                   unsigned short* ctx) {
  int bh = blockIdx.y, b = bh >> 4, h = bh & 15;
  int q0 = blockIdx.x * 128;
  int t = threadIdx.x, wave = t >> 6, lane = t & 63;
  int l31 = lane & 31, hi = lane >> 5;

  __shared__ __align__(16) char Ks[2][64 * 128];
  __shared__ __align__(16) char Vs[2][64 * 128];

  const unsigned short* Kp = K + (size_t)(b * SEQ) * D_MODEL + h * HDIM;
  const unsigned short* Vp = Vt + (size_t)bh * HDIM * SEQ;

  // Q fragments: row/col = q = lane&31, k-elems = kk*16 + hi*8 + e
  short8 qv[4];
  {
    const unsigned short* qp = Q + (size_t)(b * SEQ + q0 + wave * 32 + l31) * D_MODEL + h * HDIM + hi * 8;
#pragma unroll
    for (int kk = 0; kk < 4; ++kk) qv[kk] = *(const short8*)(qp + kk * 16);
  }

  const float SCL = 0.125f * 1.44269504f;
  float lsum = 0.f;
  f32x16 oacc[2] = {};

  // ======== pass A ========
#pragma unroll
  for (int c = 0; c < 2; ++c) {
    int idx = t + 256 * c;
    int row = idx >> 3, ch = idx & 7;
    int cb = (ch * 16) ^ ((row & 7) << 4);
    *(uint4*)(Ks[0] + row * 128 + cb) = *(const uint4*)(Kp + (size_t)row * D_MODEL + ch * 8);
    *(uint4*)(Vs[0] + row * 128 + cb) = *(const uint4*)(Vp + (size_t)row * SEQ + ch * 8);
  }
  __syncthreads();
  int cur = 0;
  for (int ti = 0; ti < 32; ++ti) {
    uint4 nk[2], nv[2];
    bool more = (ti + 1) < 32;
    if (more) {
#pragma unroll
      for (int c = 0; c < 2; ++c) {
        int idx = t + 256 * c;
        int row = idx >> 3, ch = idx & 7;
        nk[c] = *(const uint4*)(Kp + (size_t)((ti + 1) * 64 + row) * D_MODEL + ch * 8);
        nv[c] = *(const uint4*)(Vp + (size_t)row * SEQ + (ti + 1) * 64 + ch * 8);
      }
    }
    // QK^T swapped: D[k][q], A = K tile, B = Q^T
    f32x16 st[2] = {};
#pragma unroll
    for (int n = 0; n < 2; ++n)
#pragma unroll
      for (int kk = 0; kk < 4; ++kk) {
        int kr = n * 32 + l31;
        short8 ak = *(const short8*)(Ks[cur] + kr * 128 + ((kk * 32 + hi * 16) ^ ((kr & 7) << 4)));
        st[n] = __builtin_amdgcn_mfma_f32_32x32x16_bf16(ak, qv[kk], st[n], 0, 0, 0);
      }
    // exp2, row-sum, pack to bf16 pairs
    unsigned int P0[2][4], P1[2][4];
#pragma unroll
    for (int n = 0; n < 2; ++n)
#pragma unroll
      for (int j2 = 0; j2 < 4; ++j2) {
        float p0 = fexp2(st[n][4 * j2 + 0] * SCL);
        float p1 = fexp2(st[n][4 * j2 + 1] * SCL);
        float p2 = fexp2(st[n][4 * j2 + 2] * SCL);
        float p3 = fexp2(st[n][4 * j2 + 3] * SCL);
        lsum += (p0 + p1) + (p2 + p3);
        P0[n][j2] = cvtpk(p0, p1);
        P1[n][j2] = cvtpk(p2, p3);
      }
    // permlane32_swap -> A-fragments of P (row = q = lane&31, k contiguous)
    short8 pa[4];
#pragma unroll
    for (int n = 0; n < 2; ++n)
#pragma unroll
      for (int c = 0; c < 2; ++c) {
        uint2v s0 = __builtin_amdgcn_permlane32_swap(P0[n][2 * c], P0[n][2 * c + 1], false, false);
        uint2v s1 = __builtin_amdgcn_permlane32_swap(P1[n][2 * c], P1[n][2 * c + 1], false, false);
        uint4 w;
        w.x = s0.x; w.y = s1.x; w.z = s0.y; w.w = s1.y;
        pa[n * 2 + c] = *(short8*)&w;
      }
    // PV: D[q][dv] += P[q][k] * V[k][dv]
#pragma unroll
    for (int n2 = 0; n2 < 2; ++n2)
#pragma unroll
      for (int kk = 0; kk < 4; ++kk) {
        int vr = n2 * 32 + l31;
        short8 bv = *(const short8*)(Vs[cur] + vr * 128 + ((kk * 32 + hi * 16) ^ ((vr & 7) << 4)));
        oacc[n2] = __builtin_amdgcn_mfma_f32_32x32x16_bf16(pa[kk], bv, oacc[n2], 0, 0, 0);
      }
    if (more) {
#pragma unroll
      for (int c = 0; c < 2; ++c) {
        int idx = t + 256 * c;
        int row = idx >> 3, ch = idx & 7;
        int cb = (ch * 16) ^ ((row & 7) << 4);
        *(uint4*)(Ks[cur ^ 1] + row * 128 + cb) = nk[c];
        *(uint4*)(Vs[cur ^ 1] + row * 128 + cb) = nv[c];
      }
    }
    __syncthreads();
    cur ^= 1;
  }
  float tot = lsum + __shfl_xor(lsum, 32, 64);
  float inv = 1.f / tot;
  float iv16[16];
#pragma unroll
  for (int reg = 0; reg < 16; ++reg) {
    int qr = (reg & 3) + 8 * (reg >> 2) + 4 * hi;
    iv16[reg] = __shfl(inv, qr, 64);
  }
#pragma unroll
  for (int n2 = 0; n2 < 2; ++n2)
#pragma unroll
    for (int reg = 0; reg < 16; ++reg) {
      int qr = (reg & 3) + 8 * (reg >> 2) + 4 * hi;
      int row = b * SEQ + q0 + wave * 32 + qr;
      ctx[(size_t)row * D_MODEL + h * HDIM + n2 * 32 + l31] = f2bf(oacc[n2][reg] * iv16[reg]);
    }

  // ======== pass B: recompute + store normalized attention ========
  float* rowp[16];
  {
    float* abase = attn + (size_t)bh * SEQ * SEQ + l31;
#pragma unroll
    for (int reg = 0; reg < 16; ++reg) {
      int qr = (reg & 3) + 8 * (reg >> 2) + 4 * hi;
      rowp[reg] = abase + (size_t)(q0 + wave * 32 + qr) * SEQ;
    }
  }
#pragma unroll
  for (int c = 0; c < 2; ++c) {
    int idx = t + 256 * c;
    int row = idx >> 3, ch = idx & 7;
    int cb = (ch * 16) ^ ((row & 7) << 4);
    *(uint4*)(Ks[0] + row * 128 + cb) = *(const uint4*)(Kp + (size_t)row * D_MODEL + ch * 8);
  }
  __syncthreads();
  cur = 0;
  for (int ti = 0; ti < 32; ++ti) {
    uint4 nk[2];
    bool more = (ti + 1) < 32;
    if (more) {
#pragma unroll
      for (int c = 0; c < 2; ++c) {
        int idx = t + 256 * c;
        int row = idx >> 3, ch = idx & 7;
        nk[c] = *(const uint4*)(Kp + (size_t)((ti + 1) * 64 + row) * D_MODEL + ch * 8);
      }
    }
    f32x16 st[2] = {};
#pragma unroll
    for (int n = 0; n < 2; ++n)
#pragma unroll
      for (int kk = 0; kk < 4; ++kk) {
        int kr = n * 32 + l31;
        short8 bk = *(const short8*)(Ks[cur] + kr * 128 + ((kk * 32 + hi * 16) ^ ((kr & 7) << 4)));
        st[n] = __builtin_amdgcn_mfma_f32_32x32x16_bf16(qv[kk], bk, st[n], 0, 0, 0);
      }
#pragma unroll
    for (int n = 0; n < 2; ++n)
#pragma unroll
      for (int reg = 0; reg < 16; ++reg) {
        float p = fexp2(st[n][reg] * SCL) * iv16[reg];
        __builtin_nontemporal_store(p, rowp[reg] + ti * 64 + n * 32);
      }
    if (more) {
#pragma unroll
      for (int c = 0; c < 2; ++c) {
        int idx = t + 256 * c;
        int row = idx >> 3, ch = idx & 7;
        int cb = (ch * 16) ^ ((row & 7) << 4);
        *(uint4*)(Ks[cur ^ 1] + row * 128 + cb) = nk[c];
      }
    }
    __syncthreads();
    cur ^= 1;
  }
}

// ---------------------------------------------------------------------------
extern "C" void kernel_launch(void* const* d_in, const int* in_sizes, int n_in,
                              void* d_out, int out_size, void* d_ws, size_t ws_size,
                              hipStream_t stream) {
  const float* query = (const float*)d_in[0];
  const float* key   = (const float*)d_in[1];
  const float* value = (const float*)d_in[2];
  const float* Wq = (const float*)d_in[3];
  const float* bq = (const float*)d_in[4];
  const float* Wk = (const float*)d_in[5];
  const float* bk = (const float*)d_in[6];
  const float* Wv = (const float*)d_in[7];
  const float* bv = (const float*)d_in[8];
  const float* Wo = (const float*)d_in[9];
  const float* bo = (const float*)d_in[10];

  char* ws = (char*)d_ws;
  const size_t MB = (size_t)1 << 20;
  // lifetimes: Xq dead after QKV-gemm -> Cw reuses it; Xk dead -> Vtw reuses it.
  unsigned short* WqT = (unsigned short*)(ws + 0 * MB);
  unsigned short* WkT = (unsigned short*)(ws + 2 * MB);
  unsigned short* WvT = (unsigned short*)(ws + 4 * MB);
  unsigned short* WoT = (unsigned short*)(ws + 6 * MB);
  unsigned short* Xq  = (unsigned short*)(ws + 8 * MB);
  unsigned short* Xk  = (unsigned short*)(ws + 16 * MB);
  unsigned short* Xv  = (unsigned short*)(ws + 24 * MB);
  unsigned short* Qw  = (unsigned short*)(ws + 32 * MB);
  unsigned short* Kw  = (unsigned short*)(ws + 40 * MB);
  unsigned short* Vw  = (unsigned short*)(ws + 48 * MB);
  unsigned short* Vtw = (unsigned short*)(ws + 16 * MB);  // over Xk
  unsigned short* Cw  = (unsigned short*)(ws + 8 * MB);   // over Xq

  float* out0 = (float*)d_out;
  float* attn = out0 + (size_t)MROWS * D_MODEL;

  conv_kernel<<<dim3(2048, 3), 256, 0, stream>>>(query, key, value, Xq, Xk, Xv);

  WtArgs wa;
  wa.src[0] = Wq; wa.src[1] = Wk; wa.src[2] = Wv; wa.src[3] = Wo;
  wt_kernel<<<dim3(16, 16, 4), 256, 0, stream>>>(wa, WqT);

  GemmArgs ga;
  ga.A[0] = Xq; ga.A[1] = Xk; ga.A[2] = Xv;
  ga.W[0] = WqT; ga.W[1] = WkT; ga.W[2] = WvT;
  ga.bias[0] = bq; ga.bias[1] = bk; ga.bias[2] = bv;
  ga.C[0] = Qw; ga.C[1] = Kw; ga.C[2] = Vw;
  gemm_kernel<false><<<dim3(8, 32, 3), 256, 0, stream>>>(ga);

  vt_kernel<<<dim3(32, 32), 256, 0, stream>>>(Vw, Vtw);

  attn_kernel<<<dim3(16, 32), 256, 0, stream>>>(Qw, Kw, Vtw, attn, Cw);

  GemmArgs go;
  go.A[0] = Cw; go.A[1] = Cw; go.A[2] = Cw;
  go.W[0] = WoT; go.W[1] = WoT; go.W[2] = WoT;
  go.bias[0] = bo; go.bias[1] = bo; go.bias[2] = bo;
  go.C[0] = d_out; go.C[1] = d_out; go.C[2] = d_out;
  gemm_kernel<true><<<dim3(8, 32, 1), 256, 0, stream>>>(go);
}

// Round 6
// 285.622 us; speedup vs baseline: 1.6317x; 1.0399x over previous
//
#include <hip/hip_runtime.h>
#include <math.h>

#define D_MODEL 1024
#define NHEADS 16
#define HDIM 64
#define BATCH 2
#define SEQ 2048
#define MROWS (BATCH * SEQ)  // 4096

typedef unsigned int uint32;
typedef __attribute__((ext_vector_type(8))) short short8;
typedef __attribute__((ext_vector_type(4))) float f32x4;
typedef __attribute__((ext_vector_type(16))) float f32x16;
typedef __attribute__((ext_vector_type(2))) unsigned int uint2v;

__device__ __forceinline__ unsigned short f2bf(float f) {
  unsigned int u = __float_as_uint(f);
  u += 0x7fffu + ((u >> 16) & 1u);
  return (unsigned short)(u >> 16);
}

__device__ __forceinline__ float fexp2(float x) {
  float r;
  asm("v_exp_f32 %0, %1" : "=v"(r) : "v"(x));
  return r;
}

__device__ __forceinline__ unsigned int cvtpk(float lo, float hi) {
  unsigned int r;
  asm("v_cvt_pk_bf16_f32 %0, %1, %2" : "=v"(r) : "v"(lo), "v"(hi));
  return r;
}

// barrier that waits only on LDS ops (ds_write visibility) — does NOT drain
// the vmcnt store/load queue like __syncthreads does. Global->reg load deps
// are enforced by compiler data-dep waitcnts before the dependent ds_write.
__device__ __forceinline__ void bar_lgkm() {
  asm volatile("s_waitcnt lgkmcnt(0)\n\ts_barrier" ::: "memory");
}

__device__ __forceinline__ void gl_lds16(const void* g, void* l) {
  __builtin_amdgcn_global_load_lds((const __attribute__((address_space(1))) void*)g,
                                   (__attribute__((address_space(3))) void*)l, 16, 0, 0);
}

// ---------------------------------------------------------------------------
// Kernel 0: convert activations fp32 -> bf16 (query/key/value)
// ---------------------------------------------------------------------------
__global__ __launch_bounds__(256) void conv_kernel(const float* q, const float* k, const float* v,
                                                   unsigned short* xq, unsigned short* xk,
                                                   unsigned short* xv) {
  int z = blockIdx.y;
  const float* s = (z == 0) ? q : ((z == 1) ? k : v);
  unsigned short* d = (z == 0) ? xq : ((z == 1) ? xk : xv);
  int i = (blockIdx.x * 256 + threadIdx.x) * 8;
  float4 v0 = *(const float4*)(s + i);
  float4 v1 = *(const float4*)(s + i + 4);
  uint4 o;
  o.x = cvtpk(v0.x, v0.y);
  o.y = cvtpk(v0.z, v0.w);
  o.z = cvtpk(v1.x, v1.y);
  o.w = cvtpk(v1.z, v1.w);
  *(uint4*)(d + i) = o;
}

// ---------------------------------------------------------------------------
// Kernel 1: convert 4 weights fp32 [K][N] -> bf16 transposed [N][K]
// ---------------------------------------------------------------------------
struct WtArgs { const float* src[4]; };

__global__ __launch_bounds__(256) void wt_kernel(WtArgs args, unsigned short* dst) {
  const float* W = args.src[blockIdx.z];
  unsigned short* WT = dst + (size_t)blockIdx.z * (D_MODEL * D_MODEL);
  __shared__ unsigned short tile[64][80];
  int t = threadIdx.x;
  int r = t >> 2, cc = (t & 3) * 16;
  int k0 = blockIdx.y * 64, n0 = blockIdx.x * 64;
  const float* src = W + (size_t)(k0 + r) * D_MODEL + n0 + cc;
#pragma unroll
  for (int j = 0; j < 16; j += 4) {
    float4 v = *(const float4*)(src + j);
    tile[r][cc + j + 0] = f2bf(v.x);
    tile[r][cc + j + 1] = f2bf(v.y);
    tile[r][cc + j + 2] = f2bf(v.z);
    tile[r][cc + j + 3] = f2bf(v.w);
  }
  __syncthreads();
  __align__(16) unsigned short tmp[16];
#pragma unroll
  for (int j = 0; j < 16; ++j) tmp[j] = tile[cc + j][r];
  unsigned short* d = WT + (size_t)(n0 + r) * D_MODEL + k0 + cc;
  *(uint4*)d = ((uint4*)tmp)[0];
  *(uint4*)(d + 8) = ((uint4*)tmp)[1];
}

// ---------------------------------------------------------------------------
// Kernel 2/5: GEMM (m97 structure)  C[M,N] = A[M,K] * WT[N,K]^T + bias
//   128x128 tile, BK=64, global_load_lds width-16, LINEAR LDS, 4 waves.
//   1D grid with XCD-chunked remap: xcd = bid%8 owns contiguous wgid chunk.
// ---------------------------------------------------------------------------
struct GemmArgs {
  const unsigned short* A[3];
  const unsigned short* W[3];
  const float* bias[3];
  void* C[3];
};

template <bool OUT_F32>
__global__ __launch_bounds__(256) void gemm_kernel(GemmArgs args) {
  int bid = blockIdx.x;
  int wgid = (bid & 7) * (gridDim.x >> 3) + (bid >> 3);
  int x = wgid & 7;
  int yz = wgid >> 3;
  int y = yz & 31;
  int z = yz >> 5;
  const unsigned short* A = args.A[z];
  const unsigned short* WT = args.W[z];
  const float* bias = args.bias[z];
  int n0 = x * 128, m0 = y * 128;
  __shared__ __align__(16) unsigned short As[128 * 64];
  __shared__ __align__(16) unsigned short Bs[128 * 64];
  int t = threadIdx.x;
  int wave = t >> 6, lane = t & 63;
  int wm = (wave >> 1) * 64, wn = (wave & 1) * 64;
  int lr = lane & 15, lg = lane >> 4;
  int r8 = lane >> 3, c8 = (lane & 7) * 8;
  f32x4 acc[4][4] = {};

  for (int kt = 0; kt < D_MODEL; kt += 64) {
#pragma unroll
    for (int i = 0; i < 4; ++i) {
      int row = wave * 32 + i * 8;
      gl_lds16(A + (size_t)(m0 + row + r8) * D_MODEL + kt + c8, As + row * 64);
      gl_lds16(WT + (size_t)(n0 + row + r8) * D_MODEL + kt + c8, Bs + row * 64);
    }
    __syncthreads();
    short8 af[4][2], bf[4][2];
#pragma unroll
    for (int f = 0; f < 4; ++f) {
#pragma unroll
      for (int kk = 0; kk < 2; ++kk) {
        af[f][kk] = *(const short8*)((const char*)As + (wm + f * 16 + lr) * 128 + kk * 64 + lg * 16);
        bf[f][kk] = *(const short8*)((const char*)Bs + (wn + f * 16 + lr) * 128 + kk * 64 + lg * 16);
      }
    }
#pragma unroll
    for (int i = 0; i < 4; ++i)
#pragma unroll
      for (int j = 0; j < 4; ++j)
#pragma unroll
        for (int kk = 0; kk < 2; ++kk)
          acc[i][j] = __builtin_amdgcn_mfma_f32_16x16x32_bf16(af[i][kk], bf[j][kk], acc[i][j], 0, 0, 0);
    __syncthreads();
  }
#pragma unroll
  for (int i = 0; i < 4; ++i)
#pragma unroll
    for (int j = 0; j < 4; ++j) {
      int col = n0 + wn + j * 16 + lr;
      float bb = bias[col];
#pragma unroll
      for (int r = 0; r < 4; ++r) {
        int row = m0 + wm + i * 16 + lg * 4 + r;
        float v = acc[i][j][r] + bb;
        if (OUT_F32)
          ((float*)args.C[z])[(size_t)row * D_MODEL + col] = v;
        else
          ((unsigned short*)args.C[z])[(size_t)row * D_MODEL + col] = f2bf(v);
      }
    }
}

// ---------------------------------------------------------------------------
// Kernel 3: V [B*S, D] bf16 -> Vt [(b*H+h)*64 + dh][S] bf16
// ---------------------------------------------------------------------------
__global__ __launch_bounds__(256) void vt_kernel(const unsigned short* V, unsigned short* Vt) {
  int bh = blockIdx.y;
  int b = bh >> 4;
  int h = bh & 15;
  int s0 = blockIdx.x * 64;
  __shared__ unsigned short tile[64][80];
  int t = threadIdx.x;
  int r = t >> 2, c = (t & 3) * 16;
  const unsigned short* src = V + (size_t)(b * SEQ + s0 + r) * D_MODEL + h * HDIM + c;
  __align__(16) unsigned short buf[16];
  ((uint4*)buf)[0] = *(const uint4*)src;
  ((uint4*)buf)[1] = *(const uint4*)(src + 8);
#pragma unroll
  for (int j = 0; j < 16; ++j) tile[r][c + j] = buf[j];
  __syncthreads();
  __align__(16) unsigned short tmp[16];
#pragma unroll
  for (int j = 0; j < 16; ++j) tmp[j] = tile[c + j][r];
  unsigned short* dst = Vt + ((size_t)bh * HDIM + r) * SEQ + s0 + c;
  *(uint4*)dst = ((uint4*)tmp)[0];
  *(uint4*)(dst + 8) = ((uint4*)tmp)[1];
}

// ---------------------------------------------------------------------------
// Kernel 4: fused attention. Pass A: swapped QK^T (32x32x16) + exp2 + lsum
//   + T12 permlane P transpose + PV -> ctx (normalized at end).
//   Pass B: unswapped QK^T recompute + normalized nontemporal fp32 stores.
//   XCD-chunked block remap: each XCD owns 4 whole bh groups (K/V L2-local).
//   lgkm-only barriers: store queue never drained inside the tile loop.
// ---------------------------------------------------------------------------
__global__ __launch_bounds__(256) void attn_kernel(const unsigned short* Q, const unsigned short* K,
                                                   const unsigned short* Vt, float* attn,
                                                   unsigned short* ctx) {
  int bid = blockIdx.x;                      // 512 blocks
  int wgid = (bid & 7) * 64 + (bid >> 3);    // xcd-chunked remap
  int bh = wgid >> 4;
  int q0 = (wgid & 15) * 128;
  int b = bh >> 4, h = bh & 15;
  int t = threadIdx.x, wave = t >> 6, lane = t & 63;
  int l31 = lane & 31, hi = lane >> 5;

  __shared__ __align__(16) char Ks[2][64 * 128];
  __shared__ __align__(16) char Vs[2][64 * 128];

  const unsigned short* Kp = K + (size_t)(b * SEQ) * D_MODEL + h * HDIM;
  const unsigned short* Vp = Vt + (size_t)bh * HDIM * SEQ;

  // Q fragments: row/col = q = lane&31, k-elems = kk*16 + hi*8 + e
  short8 qv[4];
  {
    const unsigned short* qp = Q + (size_t)(b * SEQ + q0 + wave * 32 + l31) * D_MODEL + h * HDIM + hi * 8;
#pragma unroll
    for (int kk = 0; kk < 4; ++kk) qv[kk] = *(const short8*)(qp + kk * 16);
  }

  const float SCL = 0.125f * 1.44269504f;
  float lsum = 0.f;
  f32x16 oacc[2] = {};

  // ======== pass A ========
#pragma unroll
  for (int c = 0; c < 2; ++c) {
    int idx = t + 256 * c;
    int row = idx >> 3, ch = idx & 7;
    int cb = (ch * 16) ^ ((row & 7) << 4);
    *(uint4*)(Ks[0] + row * 128 + cb) = *(const uint4*)(Kp + (size_t)row * D_MODEL + ch * 8);
    *(uint4*)(Vs[0] + row * 128 + cb) = *(const uint4*)(Vp + (size_t)row * SEQ + ch * 8);
  }
  bar_lgkm();
  int cur = 0;
  for (int ti = 0; ti < 32; ++ti) {
    uint4 nk[2], nv[2];
    bool more = (ti + 1) < 32;
    if (more) {
#pragma unroll
      for (int c = 0; c < 2; ++c) {
        int idx = t + 256 * c;
        int row = idx >> 3, ch = idx & 7;
        nk[c] = *(const uint4*)(Kp + (size_t)((ti + 1) * 64 + row) * D_MODEL + ch * 8);
        nv[c] = *(const uint4*)(Vp + (size_t)row * SEQ + (ti + 1) * 64 + ch * 8);
      }
    }
    // QK^T swapped: D[k][q], A = K tile, B = Q^T
    f32x16 st[2] = {};
#pragma unroll
    for (int n = 0; n < 2; ++n)
#pragma unroll
      for (int kk = 0; kk < 4; ++kk) {
        int kr = n * 32 + l31;
        short8 ak = *(const short8*)(Ks[cur] + kr * 128 + ((kk * 32 + hi * 16) ^ ((kr & 7) << 4)));
        st[n] = __builtin_amdgcn_mfma_f32_32x32x16_bf16(ak, qv[kk], st[n], 0, 0, 0);
      }
    // exp2, row-sum, pack to bf16 pairs
    unsigned int P0[2][4], P1[2][4];
#pragma unroll
    for (int n = 0; n < 2; ++n)
#pragma unroll
      for (int j2 = 0; j2 < 4; ++j2) {
        float p0 = fexp2(st[n][4 * j2 + 0] * SCL);
        float p1 = fexp2(st[n][4 * j2 + 1] * SCL);
        float p2 = fexp2(st[n][4 * j2 + 2] * SCL);
        float p3 = fexp2(st[n][4 * j2 + 3] * SCL);
        lsum += (p0 + p1) + (p2 + p3);
        P0[n][j2] = cvtpk(p0, p1);
        P1[n][j2] = cvtpk(p2, p3);
      }
    // permlane32_swap -> A-fragments of P (row = q = lane&31, k contiguous)
    short8 pa[4];
#pragma unroll
    for (int n = 0; n < 2; ++n)
#pragma unroll
      for (int c = 0; c < 2; ++c) {
        uint2v s0 = __builtin_amdgcn_permlane32_swap(P0[n][2 * c], P0[n][2 * c + 1], false, false);
        uint2v s1 = __builtin_amdgcn_permlane32_swap(P1[n][2 * c], P1[n][2 * c + 1], false, false);
        uint4 w;
        w.x = s0.x; w.y = s1.x; w.z = s0.y; w.w = s1.y;
        pa[n * 2 + c] = *(short8*)&w;
      }
    // PV: D[q][dv] += P[q][k] * V[k][dv]
#pragma unroll
    for (int n2 = 0; n2 < 2; ++n2)
#pragma unroll
      for (int kk = 0; kk < 4; ++kk) {
        int vr = n2 * 32 + l31;
        short8 bv = *(const short8*)(Vs[cur] + vr * 128 + ((kk * 32 + hi * 16) ^ ((vr & 7) << 4)));
        oacc[n2] = __builtin_amdgcn_mfma_f32_32x32x16_bf16(pa[kk], bv, oacc[n2], 0, 0, 0);
      }
    if (more) {
#pragma unroll
      for (int c = 0; c < 2; ++c) {
        int idx = t + 256 * c;
        int row = idx >> 3, ch = idx & 7;
        int cb = (ch * 16) ^ ((row & 7) << 4);
        *(uint4*)(Ks[cur ^ 1] + row * 128 + cb) = nk[c];
        *(uint4*)(Vs[cur ^ 1] + row * 128 + cb) = nv[c];
      }
    }
    bar_lgkm();
    cur ^= 1;
  }
  float tot = lsum + __shfl_xor(lsum, 32, 64);
  float inv = 1.f / tot;
  float iv16[16];
#pragma unroll
  for (int reg = 0; reg < 16; ++reg) {
    int qr = (reg & 3) + 8 * (reg >> 2) + 4 * hi;
    iv16[reg] = __shfl(inv, qr, 64);
  }
#pragma unroll
  for (int n2 = 0; n2 < 2; ++n2)
#pragma unroll
    for (int reg = 0; reg < 16; ++reg) {
      int qr = (reg & 3) + 8 * (reg >> 2) + 4 * hi;
      int row = b * SEQ + q0 + wave * 32 + qr;
      ctx[(size_t)row * D_MODEL + h * HDIM + n2 * 32 + l31] = f2bf(oacc[n2][reg] * iv16[reg]);
    }

  // ======== pass B: recompute + store normalized attention ========
  float* rowp[16];
  {
    float* abase = attn + (size_t)bh * SEQ * SEQ + l31;
#pragma unroll
    for (int reg = 0; reg < 16; ++reg) {
      int qr = (reg & 3) + 8 * (reg >> 2) + 4 * hi;
      rowp[reg] = abase + (size_t)(q0 + wave * 32 + qr) * SEQ;
    }
  }
#pragma unroll
  for (int c = 0; c < 2; ++c) {
    int idx = t + 256 * c;
    int row = idx >> 3, ch = idx & 7;
    int cb = (ch * 16) ^ ((row & 7) << 4);
    *(uint4*)(Ks[0] + row * 128 + cb) = *(const uint4*)(Kp + (size_t)row * D_MODEL + ch * 8);
  }
  bar_lgkm();
  cur = 0;
  for (int ti = 0; ti < 32; ++ti) {
    uint4 nk[2];
    bool more = (ti + 1) < 32;
    if (more) {
#pragma unroll
      for (int c = 0; c < 2; ++c) {
        int idx = t + 256 * c;
        int row = idx >> 3, ch = idx & 7;
        nk[c] = *(const uint4*)(Kp + (size_t)((ti + 1) * 64 + row) * D_MODEL + ch * 8);
      }
    }
    f32x16 st[2] = {};
#pragma unroll
    for (int n = 0; n < 2; ++n)
#pragma unroll
      for (int kk = 0; kk < 4; ++kk) {
        int kr = n * 32 + l31;
        short8 bk = *(const short8*)(Ks[cur] + kr * 128 + ((kk * 32 + hi * 16) ^ ((kr & 7) << 4)));
        st[n] = __builtin_amdgcn_mfma_f32_32x32x16_bf16(qv[kk], bk, st[n], 0, 0, 0);
      }
#pragma unroll
    for (int n = 0; n < 2; ++n)
#pragma unroll
      for (int reg = 0; reg < 16; ++reg) {
        float p = fexp2(st[n][reg] * SCL) * iv16[reg];
        __builtin_nontemporal_store(p, rowp[reg] + ti * 64 + n * 32);
      }
    if (more) {
#pragma unroll
      for (int c = 0; c < 2; ++c) {
        int idx = t + 256 * c;
        int row = idx >> 3, ch = idx & 7;
        int cb = (ch * 16) ^ ((row & 7) << 4);
        *(uint4*)(Ks[cur ^ 1] + row * 128 + cb) = nk[c];
      }
    }
    bar_lgkm();
    cur ^= 1;
  }
}

// ---------------------------------------------------------------------------
extern "C" void kernel_launch(void* const* d_in, const int* in_sizes, int n_in,
                              void* d_out, int out_size, void* d_ws, size_t ws_size,
                              hipStream_t stream) {
  const float* query = (const float*)d_in[0];
  const float* key   = (const float*)d_in[1];
  const float* value = (const float*)d_in[2];
  const float* Wq = (const float*)d_in[3];
  const float* bq = (const float*)d_in[4];
  const float* Wk = (const float*)d_in[5];
  const float* bk = (const float*)d_in[6];
  const float* Wv = (const float*)d_in[7];
  const float* bv = (const float*)d_in[8];
  const float* Wo = (const float*)d_in[9];
  const float* bo = (const float*)d_in[10];

  char* ws = (char*)d_ws;
  const size_t MB = (size_t)1 << 20;
  // lifetimes: Xq dead after QKV-gemm -> Cw reuses it; Xk dead -> Vtw reuses it.
  unsigned short* WqT = (unsigned short*)(ws + 0 * MB);
  unsigned short* WkT = (unsigned short*)(ws + 2 * MB);
  unsigned short* WvT = (unsigned short*)(ws + 4 * MB);
  unsigned short* WoT = (unsigned short*)(ws + 6 * MB);
  unsigned short* Xq  = (unsigned short*)(ws + 8 * MB);
  unsigned short* Xk  = (unsigned short*)(ws + 16 * MB);
  unsigned short* Xv  = (unsigned short*)(ws + 24 * MB);
  unsigned short* Qw  = (unsigned short*)(ws + 32 * MB);
  unsigned short* Kw  = (unsigned short*)(ws + 40 * MB);
  unsigned short* Vw  = (unsigned short*)(ws + 48 * MB);
  unsigned short* Vtw = (unsigned short*)(ws + 16 * MB);  // over Xk
  unsigned short* Cw  = (unsigned short*)(ws + 8 * MB);   // over Xq

  float* out0 = (float*)d_out;
  float* attn = out0 + (size_t)MROWS * D_MODEL;

  conv_kernel<<<dim3(2048, 3), 256, 0, stream>>>(query, key, value, Xq, Xk, Xv);

  WtArgs wa;
  wa.src[0] = Wq; wa.src[1] = Wk; wa.src[2] = Wv; wa.src[3] = Wo;
  wt_kernel<<<dim3(16, 16, 4), 256, 0, stream>>>(wa, WqT);

  GemmArgs ga;
  ga.A[0] = Xq; ga.A[1] = Xk; ga.A[2] = Xv;
  ga.W[0] = WqT; ga.W[1] = WkT; ga.W[2] = WvT;
  ga.bias[0] = bq; ga.bias[1] = bk; ga.bias[2] = bv;
  ga.C[0] = Qw; ga.C[1] = Kw; ga.C[2] = Vw;
  gemm_kernel<false><<<dim3(768), 256, 0, stream>>>(ga);

  vt_kernel<<<dim3(32, 32), 256, 0, stream>>>(Vw, Vtw);

  attn_kernel<<<dim3(512), 256, 0, stream>>>(Qw, Kw, Vtw, attn, Cw);

  GemmArgs go;
  go.A[0] = Cw; go.A[1] = Cw; go.A[2] = Cw;
  go.W[0] = WoT; go.W[1] = WoT; go.W[2] = WoT;
  go.bias[0] = bo; go.bias[1] = bo; go.bias[2] = bo;
  go.C[0] = d_out; go.C[1] = d_out; go.C[2] = d_out;
  gemm_kernel<true><<<dim3(256), 256, 0, stream>>>(go);
}